// Round 8
// baseline (439.334 us; speedup 1.0000x reference)
//
#include <hip/hip_runtime.h>
#include <hip/hip_bf16.h>

typedef _Float16 half8 __attribute__((ext_vector_type(8)));
typedef __fp16 fp16x2 __attribute__((ext_vector_type(2)));
typedef float f32x4 __attribute__((ext_vector_type(4)));

#define N_DETS 8192

// ---- workspace layout (offsets in _Float16 units unless noted) ----
#define OFF_W0P   0          // 16 frags x 512 (k=9 row holds pw_b0)
#define OFF_W1P   8192       // 16x8x512
#define OFF_W2P   73728      // 2x8x512
#define OFF_FC1P  81920      // 8 x (2x4x512)
#define OFF_PW1P  114688     // 8 x (4x3x512)
#define OFF_PW2P  163840     // 8 x (4x2x512)
#define OFF_POSTP 196608     // 8 x 2 x (4x2x512)
#define OFF_OUTP  262144     // 8 x (8x2x512)
#define OFF_F1A   327680     // 8192x32 f16 (pi-frag layout), ping
#define OFF_F1B   589824     // 8192x32 f16, pong
#define OFF_PFP   1114112    // 32768 edge-tiles x 512 (pi-frags of pairFeatures)
#define OFF_FBUF_BYTES 35782656  // f32 [8192][128]

// pi slot map: physical slot (g = lane>>4, j) <-> logical k = ((j>>2)<<4) + g*4 + (j&3)
// Both MFMA operands use the same map, so products pair correctly, and the D-tile
// pair (rows 0..15, 16..31) converts to a B-frag with pure in-lane packing.

__device__ inline f32x4 mfma16(half8 a, half8 b, f32x4 c){
  return __builtin_amdgcn_mfma_f32_16x16x32_f16(a, b, c, 0, 0, 0);
}
__device__ inline half8 ldg8(const _Float16* p){ return *(const half8*)p; }
// volatile LDS read: keeps weight frags OUT of long-lived VGPRs (defeats LICM)
__device__ inline half8 ldsv(const _Float16* p){ return *(const volatile half8*)p; }

__device__ inline unsigned pkrtz(float a, float b){
  union { fp16x2 h; unsigned u; } x;
  x.h = __builtin_amdgcn_cvt_pkrtz(a, b);
  return x.u;
}
// packed f16 max/add via direct ISA (avoids hip header overload clashes)
__device__ inline unsigned hmax2u(unsigned a, unsigned b){
  unsigned r;
  asm("v_pk_max_f16 %0, %1, %2" : "=v"(r) : "v"(a), "v"(b));
  return r;
}
__device__ inline unsigned hadd2u(unsigned a, unsigned b){
  unsigned r;
  asm("v_pk_add_f16 %0, %1, %2" : "=v"(r) : "v"(a), "v"(b));
  return r;
}

// D-pair -> B-frag under pi: slots 0-3 = A rows g*4+r, slots 4-7 = B rows 16+g*4+r.
__device__ inline half8 cvtpack(f32x4 A, f32x4 B){
  union { unsigned w[4]; half8 h; } r;
  r.w[0] = pkrtz(A[0], A[1]); r.w[1] = pkrtz(A[2], A[3]);
  r.w[2] = pkrtz(B[0], B[1]); r.w[3] = pkrtz(B[2], B[3]);
  return r.h;
}

// ---- weight packing in pi order (valid as A-frags of W^T) ----
__device__ inline void packB(const float* W, int Ksrc, int Nn, _Float16* dst, int sig){
  int ns = (Ksrc + 31) >> 5;
  int t = sig / (ns * 64);
  int rem = sig - t * ns * 64;
  int s = rem >> 6;
  int l = rem & 63;
  int col = t * 16 + (l & 15);
  int g = l >> 4;
  half8 v;
#pragma unroll
  for (int j = 0; j < 8; ++j){
    int k = s*32 + ((j>>2)<<4) + g*4 + (j&3);
    v[j] = (_Float16)((k < Ksrc) ? W[k * Nn + col] : 0.f);
  }
  *(half8*)(dst + sig * 8) = v;
}

__device__ inline void packW0(const float* W, const float* bias, _Float16* dst, int sig){
  int t = sig >> 6, l = sig & 63;
  int col = t * 16 + (l & 15);
  int g = l >> 4;
  half8 v;
#pragma unroll
  for (int j = 0; j < 8; ++j){
    int k = ((j>>2)<<4) + g*4 + (j&3);
    float x = 0.f;
    if (k < 9) x = W[k * 256 + col];
    else if (k == 9) x = bias[col];
    v[j] = (_Float16)x;
  }
  *(half8*)(dst + sig * 8) = v;
}

__global__ __launch_bounds__(256) void kPrep(const float* pwW0, const float* pwb0,
    const float* pwW1, const float* pwW2,
    const float* fc1W, const float* pw1W, const float* pw2W, const float* postW, const float* outW,
    _Float16* wsh){
  int sig = blockIdx.x * 256 + threadIdx.x;
  if (sig < 1024){ packW0(pwW0, pwb0, wsh + OFF_W0P, sig); return; }
  sig -= 1024;
  if (sig < 8192){ packB(pwW1, 256, 256, wsh + OFF_W1P, sig); return; }
  sig -= 8192;
  if (sig < 1024){ packB(pwW2, 256, 32, wsh + OFF_W2P, sig); return; }
  sig -= 1024;
  int i = sig / 3840;
  int q = sig - i * 3840;
  if (q < 512){ packB(fc1W + i*4096, 128, 32, wsh + OFF_FC1P + i*4096, q); return; }
  q -= 512;
  if (q < 768){ packB(pw1W + i*6144, 96, 64, wsh + OFF_PW1P + i*6144, q); return; }
  q -= 768;
  if (q < 512){ packB(pw2W + i*4096, 64, 64, wsh + OFF_PW2P + i*4096, q); return; }
  q -= 512;
  if (q < 512){ packB(postW + i*8192, 64, 64, wsh + OFF_POSTP + i*8192, q); return; }
  q -= 512;
  if (q < 512){ packB(postW + i*8192 + 4096, 64, 64, wsh + OFF_POSTP + i*8192 + 4096, q); return; }
  q -= 512;
  packB(outW + i*8192, 64, 128, wsh + OFF_OUTP + i*8192, q);
}

// ---- fused pairwise MLP, transposed space: 128 edges/WG, 2 e-tiles/wave ----
__global__ __launch_bounds__(256) void kP(const float* scores, const float* boxes,
    const int* cI, const int* nI, const float* b1, const float* b2,
    const _Float16* W0p, const _Float16* W1p, const _Float16* W2p, _Float16* pfp){
  __shared__ __align__(16) _Float16 sbuf[2][8192];
  __shared__ __align__(16) _Float16 rawp[4096];
  int tid = threadIdx.x;
  int lane = tid & 63, wave = tid >> 6;
  const f32x4 fz = {0.f, 0.f, 0.f, 0.f};

  // prologue: issue W0 + slice0 loads (reg-staged), zero raw buffer
  half8 w0ld[4], s0ld[4];
#pragma unroll
  for (int it = 0; it < 4; ++it){
    w0ld[it] = ldg8(W0p + it*2048 + tid*8);
    s0ld[it] = ldg8(W1p + it*2048 + tid*8);
  }
  {
    half8 z = {0,0,0,0,0,0,0,0};
#pragma unroll
    for (int it = 0; it < 2; ++it) *(half8*)(rawp + it*2048 + tid*8) = z;
  }
  __syncthreads();
  if (tid < 128){
    int e = blockIdx.x*128 + tid;
    int c = cI[e], n = nI[e];
    float cx1 = boxes[c*4+0], cy1 = boxes[c*4+1], cx2 = boxes[c*4+2], cy2 = boxes[c*4+3];
    float nx1 = boxes[n*4+0], ny1 = boxes[n*4+1], nx2 = boxes[n*4+2], ny2 = boxes[n*4+3];
    float cw = cx2-cx1, ch = cy2-cy1, nw = nx2-nx1, nh = ny2-ny1;
    float ca = cw*ch, na = nw*nh;
    float ix = fmaxf(fminf(cx2,nx2) - fmaxf(cx1,nx1), 0.f);
    float iy = fmaxf(fminf(cy2,ny2) - fmaxf(cy1,ny1), 0.f);
    float inter = ix*iy;
    float iou = inter / (ca + na - inter);
    float cs = (cw + ch) * 0.5f;
    float xd = (nx1 + nw*0.5f) - (cx1 + cw*0.5f);
    float yd = (ny1 + nh*0.5f) - (cy1 + ch*0.5f);
    float l2 = sqrtf(xd*xd + yd*yd) / cs;
    float wd = log2f(nw/cw), hd = log2f(nh/ch);
    float ad = log2f(nw/nh) - log2f(cw/ch);
    float rv[10] = {scores[c], scores[n], iou, xd/cs, yd/cs, l2, wd, hd, ad, 1.0f};
    int base = (tid >> 4) * 512;   // e-tile region
    int r = tid & 15;
#pragma unroll
    for (int k = 0; k < 10; ++k)
      rawp[base + (((k>>2)&3)*16 + r)*8 + (k&3)] = (_Float16)rv[k];   // pi position
  }
#pragma unroll
  for (int it = 0; it < 4; ++it){
    *(half8*)(&sbuf[0][0] + it*2048 + tid*8) = w0ld[it];
    *(half8*)(&sbuf[1][0] + it*2048 + tid*8) = s0ld[it];
  }
  __syncthreads();

  // L0: h0T = W0T * rawT  (bias folded via raw[9]=1)
  half8 h0f[2][8];
#pragma unroll
  for (int et = 0; et < 2; ++et){
    half8 braw = *(const half8*)(rawp + ((wave*2+et)*64 + lane)*8);
#pragma unroll
    for (int mp = 0; mp < 8; ++mp){
      f32x4 a = mfma16(*(const half8*)(&sbuf[0][0] + (2*mp)*512   + lane*8), braw, fz);
      f32x4 b = mfma16(*(const half8*)(&sbuf[0][0] + (2*mp+1)*512 + lane*8), braw, fz);
#pragma unroll
      for (int r = 0; r < 4; ++r){ a[r] = fmaxf(a[r], 0.f); b[r] = fmaxf(b[r], 0.f); }
      h0f[et][mp] = cvtpack(a, b);
    }
  }
  __syncthreads();   // protect sbuf[0] before slice1 is written into it

  // L1 + fused L2: loop over 8 output m-pairs of h1, double-buffered slices
  int q = lane >> 4;
  f32x4 apf[2][2];
  apf[0][0] = fz; apf[0][1] = fz; apf[1][0] = fz; apf[1][1] = fz;
  for (int mp = 0; mp < 8; ++mp){
    const _Float16* cur = &sbuf[(mp+1)&1][0];
    half8 stg[4];
    if (mp < 7){
#pragma unroll
      for (int it = 0; it < 4; ++it)
        stg[it] = ldg8(W1p + (mp+1)*8192 + it*2048 + tid*8);
    }
    f32x4 acc[2][2];
    acc[0][0] = fz; acc[0][1] = fz; acc[1][0] = fz; acc[1][1] = fz;
#pragma unroll
    for (int s = 0; s < 8; ++s){
      half8 A0 = *(const half8*)(cur + s*512       + lane*8);
      half8 A1 = *(const half8*)(cur + (8+s)*512   + lane*8);
#pragma unroll
      for (int et = 0; et < 2; ++et){
        acc[et][0] = mfma16(A0, h0f[et][s], acc[et][0]);
        acc[et][1] = mfma16(A1, h0f[et][s], acc[et][1]);
      }
    }
    f32x4 bv0 = *(const f32x4*)(b1 + mp*32 + q*4);
    f32x4 bv1 = *(const f32x4*)(b1 + mp*32 + 16 + q*4);
    half8 w2a = ldg8(W2p + mp*512 + lane*8);
    half8 w2b = ldg8(W2p + (8+mp)*512 + lane*8);
#pragma unroll
    for (int et = 0; et < 2; ++et){
      f32x4 ra, rb;
#pragma unroll
      for (int r = 0; r < 4; ++r){
        ra[r] = fmaxf(acc[et][0][r] + bv0[r], 0.f);
        rb[r] = fmaxf(acc[et][1][r] + bv1[r], 0.f);
      }
      half8 h1f = cvtpack(ra, rb);
      apf[et][0] = mfma16(w2a, h1f, apf[et][0]);
      apf[et][1] = mfma16(w2b, h1f, apf[et][1]);
    }
    if (mp < 7){
      _Float16* nxt = &sbuf[mp&1][0];
#pragma unroll
      for (int it = 0; it < 4; ++it)
        *(half8*)(nxt + it*2048 + tid*8) = stg[it];
    }
    __syncthreads();
  }
  // epilogue: pf = relu(pfT + b2) -> pi-frag -> store
  f32x4 c0 = *(const f32x4*)(b2 + q*4);
  f32x4 c1 = *(const f32x4*)(b2 + 16 + q*4);
#pragma unroll
  for (int et = 0; et < 2; ++et){
    f32x4 ra, rb;
#pragma unroll
    for (int r = 0; r < 4; ++r){
      ra[r] = fmaxf(apf[et][0][r] + c0[r], 0.f);
      rb[r] = fmaxf(apf[et][1][r] + c1[r], 0.f);
    }
    half8 pf = cvtpack(ra, rb);
    *(half8*)(pfp + (blockIdx.x*8 + wave*2 + et)*512 + lane*8) = pf;
  }
}

// ---- initial f1 (transposed), 16 dets per wave, 4 waves/WG ----
__global__ __launch_bounds__(256) void kF1(const float* detF, const _Float16* fc1p,
    const float* fb, _Float16* f1G){
  int lane = threadIdx.x & 63, wave = threadIdx.x >> 6;
  int q = lane >> 4, e = lane & 15;
  int det = (blockIdx.x * 4 + wave) * 16 + e;
  const f32x4 fz = {0.f, 0.f, 0.f, 0.f};
  half8 ff[4];
#pragma unroll
  for (int s = 0; s < 4; ++s){
    const float* p = detF + det*128 + s*32 + q*4;
    f32x4 x0 = *(const f32x4*)(p);
    f32x4 x1 = *(const f32x4*)(p + 16);
    union { unsigned w[4]; half8 h; } u;
    u.w[0] = pkrtz(x0[0], x0[1]); u.w[1] = pkrtz(x0[2], x0[3]);
    u.w[2] = pkrtz(x1[0], x1[1]); u.w[3] = pkrtz(x1[2], x1[3]);
    ff[s] = u.h;
  }
#pragma unroll
  for (int m = 0; m < 2; ++m){
    f32x4 a = fz;
#pragma unroll
    for (int s = 0; s < 4; ++s)
      a = mfma16(ldg8(fc1p + (m*4+s)*512 + lane*8), ff[s], a);
    f32x4 bv = *(const f32x4*)(fb + m*16 + q*4);
    unsigned u0 = pkrtz(fmaxf(a[0]+bv[0],0.f), fmaxf(a[1]+bv[1],0.f));
    unsigned u1 = pkrtz(fmaxf(a[2]+bv[2],0.f), fmaxf(a[3]+bv[3],0.f));
    *(unsigned*)(f1G + det*32 + q*8 + m*4)     = u0;
    *(unsigned*)(f1G + det*32 + q*8 + m*4 + 2) = u1;
  }
}

// ---- one graph block: edge MLP + segment max + post MLPs + residual + next f1 ----
// grid 1024 x 256: 8 dets/WG, 2 dets/wave; XCD-bijective swizzle for pfp L2 residency.
// pw1/pw2 weights live in LDS (volatile reads) so VGPR stays ~<=128 -> 4 waves/SIMD.
__global__ __launch_bounds__(256) void kBlk(const _Float16* pfp, const _Float16* f1in,
    _Float16* f1out, const int* nI, const _Float16* pw1p, const _Float16* pw2p,
    const _Float16* post0p, const _Float16* post1p, const _Float16* outp, const _Float16* fc1pn,
    const float* bb1, const float* bb2, const float* pb0, const float* pb1, const float* ob,
    const float* fbn, const float* fin, float* fout, int doF1){
  __shared__ __align__(16) _Float16 sW1[6144];   // 12 KB pw1 frags
  __shared__ __align__(16) _Float16 sW2[4096];   // 8 KB pw2 frags
  __shared__ __align__(16) _Float16 poolS[512];  // [2 halves][8 dets][32 halfs]
  int tid = threadIdx.x, lane = tid & 63, wave = tid >> 6;
  int q = lane >> 4, e = lane & 15;
  int bid = blockIdx.x;
  int swz = (bid & 7) * 128 + (bid >> 3);   // 1024 WGs: det-range <-> XCD binding
  int base = swz * 8;
  const f32x4 fz = {0.f, 0.f, 0.f, 0.f};

  // stage edge-MLP weights into LDS (1280 half8 groups over 256 threads)
  for (int u = tid; u < 1280; u += 256){
    if (u < 768) *(half8*)(sW1 + u*8)       = ldg8(pw1p + u*8);
    else         *(half8*)(sW2 + (u-768)*8) = ldg8(pw2p + (u-768)*8);
  }
  f32x4 b1v[4];
#pragma unroll
  for (int m = 0; m < 4; ++m) b1v[m] = *(const f32x4*)(bb1 + m*16 + q*4);
  unsigned b2p[8];   // pw2 bias, packed to match cvtpack slot order
#pragma unroll
  for (int m = 0; m < 4; ++m){
    b2p[m*2+0] = pkrtz(bb2[m*16 + q*4 + 0], bb2[m*16 + q*4 + 1]);
    b2p[m*2+1] = pkrtz(bb2[m*16 + q*4 + 2], bb2[m*16 + q*4 + 3]);
  }
  __syncthreads();

  // ---- phase A: edge MLP + packed-f16 pooling (2 dets per wave, serial) ----
#pragma unroll 1
  for (int dd = 0; dd < 2; ++dd){
    int d = wave*2 + dd;
    int det = base + d;
    half8 Bc = ldg8(f1in + det*32 + q*8);   // cIdxs == det for every edge of det
    int nn[4];
#pragma unroll
    for (int et = 0; et < 4; ++et) nn[et] = nI[det*64 + et*16 + e];
    half8 Bpf[4], Bn[4];
#pragma unroll
    for (int et = 0; et < 4; ++et){
      Bpf[et] = ldg8(pfp + (det*4+et)*512 + lane*8);
      Bn[et]  = ldg8(f1in + nn[et]*32 + q*8);
    }
    unsigned pm[8];
#pragma unroll
    for (int i = 0; i < 8; ++i) pm[i] = 0xFC00FC00u;   // (-inf, -inf)
#pragma unroll
    for (int et = 0; et < 4; ++et){
      f32x4 acc[4];
#pragma unroll
      for (int m = 0; m < 4; ++m){
        acc[m] = mfma16(ldsv(sW1 + (m*3+0)*512 + lane*8), Bpf[et], fz);
        acc[m] = mfma16(ldsv(sW1 + (m*3+1)*512 + lane*8), Bc, acc[m]);
        acc[m] = mfma16(ldsv(sW1 + (m*3+2)*512 + lane*8), Bn[et], acc[m]);
      }
      f32x4 r0, r1, r2, r3;
#pragma unroll
      for (int r = 0; r < 4; ++r){
        r0[r] = fmaxf(acc[0][r] + b1v[0][r], 0.f);
        r1[r] = fmaxf(acc[1][r] + b1v[1][r], 0.f);
        r2[r] = fmaxf(acc[2][r] + b1v[2][r], 0.f);
        r3[r] = fmaxf(acc[3][r] + b1v[3][r], 0.f);
      }
      half8 h1a = cvtpack(r0, r1);
      half8 h1b = cvtpack(r2, r3);
      f32x4 a2[4];
#pragma unroll
      for (int m = 0; m < 4; ++m){
        a2[m] = mfma16(ldsv(sW2 + (m*2+0)*512 + lane*8), h1a, fz);
        a2[m] = mfma16(ldsv(sW2 + (m*2+1)*512 + lane*8), h1b, a2[m]);
      }
      // pack raw a2 (bias+relu deferred past the max) and pk-max accumulate
      union { half8 h; unsigned w[4]; } uA, uB;
      uA.h = cvtpack(a2[0], a2[1]);
      uB.h = cvtpack(a2[2], a2[3]);
#pragma unroll
      for (int i = 0; i < 4; ++i){
        pm[i]   = hmax2u(pm[i],   uA.w[i]);
        pm[4+i] = hmax2u(pm[4+i], uB.w[i]);
      }
    }
    // butterfly max over the 16 edge columns (packed)
#pragma unroll
    for (int s = 1; s <= 8; s <<= 1){
#pragma unroll
      for (int i = 0; i < 8; ++i)
        pm[i] = hmax2u(pm[i], __shfl_xor(pm[i], s));
    }
    // deferred bias + relu (packed)
#pragma unroll
    for (int i = 0; i < 8; ++i)
      pm[i] = hmax2u(hadd2u(pm[i], b2p[i]), 0u);
    if (e == 0){
      union { unsigned w[4]; half8 h; } o0, o1;
#pragma unroll
      for (int i = 0; i < 4; ++i){ o0.w[i] = pm[i]; o1.w[i] = pm[4+i]; }
      *(half8*)(poolS + d*32 + q*8)       = o0.h;   // k 0..31
      *(half8*)(poolS + 256 + d*32 + q*8) = o1.h;   // k 32..63
    }
  }
  __syncthreads();

  // ---- phase B: post MLPs + residual + next f1 (8 dets as frag cols 0..7) ----
  int e8 = e & 7;
  half8 Bp0 = *(const half8*)(poolS + e8*32 + q*8);
  half8 Bp1 = *(const half8*)(poolS + 256 + e8*32 + q*8);
  int det = base + e8;
  f32x4 t0[4];
#pragma unroll
  for (int m = 0; m < 4; ++m){
    f32x4 a = mfma16(ldg8(post0p + (m*2)*512   + lane*8), Bp0, fz);
    a = mfma16(ldg8(post0p + (m*2+1)*512 + lane*8), Bp1, a);
    f32x4 bv = *(const f32x4*)(pb0 + m*16 + q*4);
#pragma unroll
    for (int r = 0; r < 4; ++r) t0[m][r] = fmaxf(a[r] + bv[r], 0.f);
  }
  half8 p1a = cvtpack(t0[0], t0[1]);
  half8 p1b = cvtpack(t0[2], t0[3]);
#pragma unroll
  for (int m = 0; m < 4; ++m){
    f32x4 a = mfma16(ldg8(post1p + (m*2)*512   + lane*8), p1a, fz);
    a = mfma16(ldg8(post1p + (m*2+1)*512 + lane*8), p1b, a);
    f32x4 bv = *(const f32x4*)(pb1 + m*16 + q*4);
#pragma unroll
    for (int r = 0; r < 4; ++r) t0[m][r] = fmaxf(a[r] + bv[r], 0.f);
  }
  half8 p2a = cvtpack(t0[0], t0[1]);
  half8 p2b = cvtpack(t0[2], t0[3]);
  f32x4 fr[8];
#pragma unroll
  for (int m = 0; m < 8; ++m){
    f32x4 a = mfma16(ldg8(outp + (m*2)*512   + lane*8), p2a, fz);
    a = mfma16(ldg8(outp + (m*2+1)*512 + lane*8), p2b, a);
    f32x4 bv = *(const f32x4*)(ob + m*16 + q*4);
    f32x4 fv = *(const f32x4*)(fin + det*128 + m*16 + q*4);
#pragma unroll
    for (int r = 0; r < 4; ++r) fr[m][r] = fmaxf(fv[r] + a[r] + bv[r], 0.f);
  }
  if (e < 8){
#pragma unroll
    for (int mm = 0; mm < 2; ++mm){
      int m = wave*2 + mm;
      *(f32x4*)(fout + det*128 + m*16 + q*4) = fr[m];
    }
  }
  if (doF1 && wave == 0){
    half8 ff[4];
#pragma unroll
    for (int s = 0; s < 4; ++s) ff[s] = cvtpack(fr[2*s], fr[2*s+1]);
#pragma unroll
    for (int m = 0; m < 2; ++m){
      f32x4 a = fz;
#pragma unroll
      for (int s = 0; s < 4; ++s)
        a = mfma16(ldg8(fc1pn + (m*4+s)*512 + lane*8), ff[s], a);
      f32x4 bv = *(const f32x4*)(fbn + m*16 + q*4);
      unsigned u0 = pkrtz(fmaxf(a[0]+bv[0],0.f), fmaxf(a[1]+bv[1],0.f));
      unsigned u1 = pkrtz(fmaxf(a[2]+bv[2],0.f), fmaxf(a[3]+bv[3],0.f));
      if (e < 8){
        *(unsigned*)(f1out + det*32 + q*8 + m*4)     = u0;
        *(unsigned*)(f1out + det*32 + q*8 + m*4 + 2) = u1;
      }
    }
  }
}

extern "C" void kernel_launch(void* const* d_in, const int* in_sizes, int n_in,
                              void* d_out, int out_size, void* d_ws, size_t ws_size,
                              hipStream_t stream){
  const float* detScores   = (const float*)d_in[0];
  const float* dtBoxes     = (const float*)d_in[1];
  const float* detFeatures = (const float*)d_in[2];
  const int*   cI          = (const int*)d_in[3];
  const int*   nI          = (const int*)d_in[4];
  const float* pwW0 = (const float*)d_in[5];
  const float* pwb0 = (const float*)d_in[6];
  const float* pwW1 = (const float*)d_in[7];
  const float* pwb1 = (const float*)d_in[8];
  const float* pwW2 = (const float*)d_in[9];
  const float* pwb2 = (const float*)d_in[10];
  const float* fc1W = (const float*)d_in[11];
  const float* fc1b = (const float*)d_in[12];
  const float* pw1W = (const float*)d_in[13];
  const float* pw1b = (const float*)d_in[14];
  const float* pw2W = (const float*)d_in[15];
  const float* pw2b = (const float*)d_in[16];
  const float* postW = (const float*)d_in[17];
  const float* postb = (const float*)d_in[18];
  const float* outW  = (const float*)d_in[19];
  const float* outb  = (const float*)d_in[20];

  _Float16* wsh  = (_Float16*)d_ws;
  float*    fbuf = (float*)((char*)d_ws + OFF_FBUF_BYTES);
  _Float16* f1A  = wsh + OFF_F1A;
  _Float16* f1B  = wsh + OFF_F1B;
  _Float16* pfp  = wsh + OFF_PFP;

  kPrep<<<160, 256, 0, stream>>>(pwW0, pwb0, pwW1, pwW2, fc1W, pw1W, pw2W, postW, outW, wsh);
  kF1<<<128, 256, 0, stream>>>(detFeatures, wsh + OFF_FC1P, fc1b, f1A);
  kP<<<4096, 256, 0, stream>>>(detScores, dtBoxes, cI, nI, pwb1, pwb2,
      wsh + OFF_W0P, wsh + OFF_W1P, wsh + OFF_W2P, pfp);

  for (int i = 0; i < 8; ++i){
    int last = (i == 7);
    _Float16* fin1  = (i & 1) ? f1B : f1A;
    _Float16* fout1 = (i & 1) ? f1A : f1B;
    kBlk<<<1024, 256, 0, stream>>>(pfp, fin1, fout1, nI,
        wsh + OFF_PW1P + i*6144, wsh + OFF_PW2P + i*4096,
        wsh + OFF_POSTP + i*8192, wsh + OFF_POSTP + i*8192 + 4096, wsh + OFF_OUTP + i*8192,
        wsh + OFF_FC1P + ((i+1) & 7)*4096,
        pw1b + i*64, pw2b + i*64, postb + i*128, postb + i*128 + 64, outb + i*128,
        fc1b + ((i+1) & 7)*32,
        (i == 0) ? detFeatures : fbuf, last ? (float*)d_out : fbuf, last ? 0 : 1);
  }
}

// Round 9
// 286.259 us; speedup vs baseline: 1.5347x; 1.5347x over previous
//
#include <hip/hip_runtime.h>
#include <hip/hip_bf16.h>

typedef _Float16 half8 __attribute__((ext_vector_type(8)));
typedef __fp16 fp16x2 __attribute__((ext_vector_type(2)));
typedef float f32x4 __attribute__((ext_vector_type(4)));

#define N_DETS 8192

// ---- workspace layout (offsets in _Float16 units unless noted) ----
#define OFF_W0P   0          // 16 frags x 512 (k=9 row holds pw_b0)
#define OFF_W1P   8192       // 16x8x512
#define OFF_W2P   73728      // 2x8x512
#define OFF_FC1P  81920      // 8 x (2x4x512)
#define OFF_PW1P  114688     // 8 x (4x3x512)
#define OFF_PW2P  163840     // 8 x (4x2x512)
#define OFF_POSTP 196608     // 8 x 2 x (4x2x512)
#define OFF_OUTP  262144     // 8 x (8x2x512)
#define OFF_F1A   327680     // 8192x32 f16 (pi-frag layout), ping
#define OFF_F1B   589824     // 8192x32 f16, pong
#define OFF_PFP   1114112    // 32768 edge-tiles x 512 (pi-frags of pairFeatures)
#define OFF_FBUF_BYTES 35782656  // f32 [8192][128]

// pi slot map: physical slot (g = lane>>4, j) <-> logical k = ((j>>2)<<4) + g*4 + (j&3)
// Both MFMA operands use the same map, so products pair correctly, and the D-tile
// pair (rows 0..15, 16..31) converts to a B-frag with pure in-lane packing.

__device__ inline f32x4 mfma16(half8 a, half8 b, f32x4 c){
  return __builtin_amdgcn_mfma_f32_16x16x32_f16(a, b, c, 0, 0, 0);
}
__device__ inline half8 ldg8(const _Float16* p){ return *(const half8*)p; }

__device__ inline unsigned pkrtz(float a, float b){
  union { fp16x2 h; unsigned u; } x;
  x.h = __builtin_amdgcn_cvt_pkrtz(a, b);
  return x.u;
}
// packed f16 max/add via direct ISA (avoids hip header overload clashes)
__device__ inline unsigned hmax2u(unsigned a, unsigned b){
  unsigned r;
  asm("v_pk_max_f16 %0, %1, %2" : "=v"(r) : "v"(a), "v"(b));
  return r;
}
__device__ inline unsigned hadd2u(unsigned a, unsigned b){
  unsigned r;
  asm("v_pk_add_f16 %0, %1, %2" : "=v"(r) : "v"(a), "v"(b));
  return r;
}

// D-pair -> B-frag under pi: slots 0-3 = A rows g*4+r, slots 4-7 = B rows 16+g*4+r.
__device__ inline half8 cvtpack(f32x4 A, f32x4 B){
  union { unsigned w[4]; half8 h; } r;
  r.w[0] = pkrtz(A[0], A[1]); r.w[1] = pkrtz(A[2], A[3]);
  r.w[2] = pkrtz(B[0], B[1]); r.w[3] = pkrtz(B[2], B[3]);
  return r.h;
}

// ---- weight packing in pi order (valid as A-frags of W^T) ----
__device__ inline void packB(const float* W, int Ksrc, int Nn, _Float16* dst, int sig){
  int ns = (Ksrc + 31) >> 5;
  int t = sig / (ns * 64);
  int rem = sig - t * ns * 64;
  int s = rem >> 6;
  int l = rem & 63;
  int col = t * 16 + (l & 15);
  int g = l >> 4;
  half8 v;
#pragma unroll
  for (int j = 0; j < 8; ++j){
    int k = s*32 + ((j>>2)<<4) + g*4 + (j&3);
    v[j] = (_Float16)((k < Ksrc) ? W[k * Nn + col] : 0.f);
  }
  *(half8*)(dst + sig * 8) = v;
}

__device__ inline void packW0(const float* W, const float* bias, _Float16* dst, int sig){
  int t = sig >> 6, l = sig & 63;
  int col = t * 16 + (l & 15);
  int g = l >> 4;
  half8 v;
#pragma unroll
  for (int j = 0; j < 8; ++j){
    int k = ((j>>2)<<4) + g*4 + (j&3);
    float x = 0.f;
    if (k < 9) x = W[k * 256 + col];
    else if (k == 9) x = bias[col];
    v[j] = (_Float16)x;
  }
  *(half8*)(dst + sig * 8) = v;
}

__global__ __launch_bounds__(256) void kPrep(const float* pwW0, const float* pwb0,
    const float* pwW1, const float* pwW2,
    const float* fc1W, const float* pw1W, const float* pw2W, const float* postW, const float* outW,
    _Float16* wsh){
  int sig = blockIdx.x * 256 + threadIdx.x;
  if (sig < 1024){ packW0(pwW0, pwb0, wsh + OFF_W0P, sig); return; }
  sig -= 1024;
  if (sig < 8192){ packB(pwW1, 256, 256, wsh + OFF_W1P, sig); return; }
  sig -= 8192;
  if (sig < 1024){ packB(pwW2, 256, 32, wsh + OFF_W2P, sig); return; }
  sig -= 1024;
  int i = sig / 3840;
  int q = sig - i * 3840;
  if (q < 512){ packB(fc1W + i*4096, 128, 32, wsh + OFF_FC1P + i*4096, q); return; }
  q -= 512;
  if (q < 768){ packB(pw1W + i*6144, 96, 64, wsh + OFF_PW1P + i*6144, q); return; }
  q -= 768;
  if (q < 512){ packB(pw2W + i*4096, 64, 64, wsh + OFF_PW2P + i*4096, q); return; }
  q -= 512;
  if (q < 512){ packB(postW + i*8192, 64, 64, wsh + OFF_POSTP + i*8192, q); return; }
  q -= 512;
  if (q < 512){ packB(postW + i*8192 + 4096, 64, 64, wsh + OFF_POSTP + i*8192 + 4096, q); return; }
  q -= 512;
  packB(outW + i*8192, 64, 128, wsh + OFF_OUTP + i*8192, q);
}

// ---- fused pairwise MLP: 256 edges/WG (512 thr, 8 waves), 2 e-tiles/wave ----
__global__ __launch_bounds__(512) void kP(const float* scores, const float* boxes,
    const int* cI, const int* nI, const float* b1, const float* b2,
    const _Float16* W0p, const _Float16* W1p, const _Float16* W2p, _Float16* pfp){
  __shared__ __align__(16) _Float16 sbuf[2][8192];
  __shared__ __align__(16) _Float16 rawp[8192];
  int tid = threadIdx.x;
  int lane = tid & 63, wave = tid >> 6;
  const f32x4 fz = {0.f, 0.f, 0.f, 0.f};

  // prologue: issue W0 + slice0 loads (reg-staged), zero raw buffer
  half8 w0ld[2], s0ld[2];
#pragma unroll
  for (int it = 0; it < 2; ++it){
    w0ld[it] = ldg8(W0p + it*4096 + tid*8);
    s0ld[it] = ldg8(W1p + it*4096 + tid*8);
  }
  {
    half8 z = {0,0,0,0,0,0,0,0};
#pragma unroll
    for (int it = 0; it < 2; ++it) *(half8*)(rawp + it*4096 + tid*8) = z;
  }
  __syncthreads();
  if (tid < 256){
    int e = blockIdx.x*256 + tid;
    int c = cI[e], n = nI[e];
    float cx1 = boxes[c*4+0], cy1 = boxes[c*4+1], cx2 = boxes[c*4+2], cy2 = boxes[c*4+3];
    float nx1 = boxes[n*4+0], ny1 = boxes[n*4+1], nx2 = boxes[n*4+2], ny2 = boxes[n*4+3];
    float cw = cx2-cx1, ch = cy2-cy1, nw = nx2-nx1, nh = ny2-ny1;
    float ca = cw*ch, na = nw*nh;
    float ix = fmaxf(fminf(cx2,nx2) - fmaxf(cx1,nx1), 0.f);
    float iy = fmaxf(fminf(cy2,ny2) - fmaxf(cy1,ny1), 0.f);
    float inter = ix*iy;
    float iou = inter / (ca + na - inter);
    float cs = (cw + ch) * 0.5f;
    float xd = (nx1 + nw*0.5f) - (cx1 + cw*0.5f);
    float yd = (ny1 + nh*0.5f) - (cy1 + ch*0.5f);
    float l2 = sqrtf(xd*xd + yd*yd) / cs;
    float wd = log2f(nw/cw), hd = log2f(nh/ch);
    float ad = log2f(nw/nh) - log2f(cw/ch);
    float rv[10] = {scores[c], scores[n], iou, xd/cs, yd/cs, l2, wd, hd, ad, 1.0f};
    int base = (tid >> 4) * 512;   // e-tile region (16 tiles)
    int r = tid & 15;
#pragma unroll
    for (int k = 0; k < 10; ++k)
      rawp[base + (((k>>2)&3)*16 + r)*8 + (k&3)] = (_Float16)rv[k];   // pi position
  }
#pragma unroll
  for (int it = 0; it < 2; ++it){
    *(half8*)(&sbuf[0][0] + it*4096 + tid*8) = w0ld[it];
    *(half8*)(&sbuf[1][0] + it*4096 + tid*8) = s0ld[it];
  }
  __syncthreads();

  // L0: h0T = W0T * rawT  (bias folded via raw[9]=1)
  half8 h0f[2][8];
#pragma unroll
  for (int et = 0; et < 2; ++et){
    half8 braw = *(const half8*)(rawp + ((wave*2+et)*64 + lane)*8);
#pragma unroll
    for (int mp = 0; mp < 8; ++mp){
      f32x4 a = mfma16(*(const half8*)(&sbuf[0][0] + (2*mp)*512   + lane*8), braw, fz);
      f32x4 b = mfma16(*(const half8*)(&sbuf[0][0] + (2*mp+1)*512 + lane*8), braw, fz);
#pragma unroll
      for (int r = 0; r < 4; ++r){ a[r] = fmaxf(a[r], 0.f); b[r] = fmaxf(b[r], 0.f); }
      h0f[et][mp] = cvtpack(a, b);
    }
  }
  __syncthreads();   // protect sbuf[0] before slice1 is written into it

  // L1 + fused L2: loop over 8 output m-pairs of h1, double-buffered slices
  int q = lane >> 4;
  f32x4 apf[2][2];
  apf[0][0] = fz; apf[0][1] = fz; apf[1][0] = fz; apf[1][1] = fz;
  for (int mp = 0; mp < 8; ++mp){
    const _Float16* cur = &sbuf[(mp+1)&1][0];
    half8 stg[2];
    if (mp < 7){
#pragma unroll
      for (int it = 0; it < 2; ++it)
        stg[it] = ldg8(W1p + (mp+1)*8192 + it*4096 + tid*8);
    }
    f32x4 acc[2][2];
    acc[0][0] = fz; acc[0][1] = fz; acc[1][0] = fz; acc[1][1] = fz;
#pragma unroll
    for (int s = 0; s < 8; ++s){
      half8 A0 = *(const half8*)(cur + s*512       + lane*8);
      half8 A1 = *(const half8*)(cur + (8+s)*512   + lane*8);
#pragma unroll
      for (int et = 0; et < 2; ++et){
        acc[et][0] = mfma16(A0, h0f[et][s], acc[et][0]);
        acc[et][1] = mfma16(A1, h0f[et][s], acc[et][1]);
      }
    }
    f32x4 bv0 = *(const f32x4*)(b1 + mp*32 + q*4);
    f32x4 bv1 = *(const f32x4*)(b1 + mp*32 + 16 + q*4);
    half8 w2a = ldg8(W2p + mp*512 + lane*8);
    half8 w2b = ldg8(W2p + (8+mp)*512 + lane*8);
#pragma unroll
    for (int et = 0; et < 2; ++et){
      f32x4 ra, rb;
#pragma unroll
      for (int r = 0; r < 4; ++r){
        ra[r] = fmaxf(acc[et][0][r] + bv0[r], 0.f);
        rb[r] = fmaxf(acc[et][1][r] + bv1[r], 0.f);
      }
      half8 h1f = cvtpack(ra, rb);
      apf[et][0] = mfma16(w2a, h1f, apf[et][0]);
      apf[et][1] = mfma16(w2b, h1f, apf[et][1]);
    }
    if (mp < 7){
      _Float16* nxt = &sbuf[mp&1][0];
#pragma unroll
      for (int it = 0; it < 2; ++it)
        *(half8*)(nxt + it*4096 + tid*8) = stg[it];
    }
    __syncthreads();
  }
  // epilogue: pf = relu(pfT + b2) -> pi-frag -> store
  f32x4 c0 = *(const f32x4*)(b2 + q*4);
  f32x4 c1 = *(const f32x4*)(b2 + 16 + q*4);
#pragma unroll
  for (int et = 0; et < 2; ++et){
    f32x4 ra, rb;
#pragma unroll
    for (int r = 0; r < 4; ++r){
      ra[r] = fmaxf(apf[et][0][r] + c0[r], 0.f);
      rb[r] = fmaxf(apf[et][1][r] + c1[r], 0.f);
    }
    half8 pf = cvtpack(ra, rb);
    *(half8*)(pfp + (blockIdx.x*16 + wave*2 + et)*512 + lane*8) = pf;
  }
}

// ---- initial f1 (transposed), 16 dets per wave, 4 waves/WG ----
__global__ __launch_bounds__(256) void kF1(const float* detF, const _Float16* fc1p,
    const float* fb, _Float16* f1G){
  int lane = threadIdx.x & 63, wave = threadIdx.x >> 6;
  int q = lane >> 4, e = lane & 15;
  int det = (blockIdx.x * 4 + wave) * 16 + e;
  const f32x4 fz = {0.f, 0.f, 0.f, 0.f};
  half8 ff[4];
#pragma unroll
  for (int s = 0; s < 4; ++s){
    const float* p = detF + det*128 + s*32 + q*4;
    f32x4 x0 = *(const f32x4*)(p);
    f32x4 x1 = *(const f32x4*)(p + 16);
    union { unsigned w[4]; half8 h; } u;
    u.w[0] = pkrtz(x0[0], x0[1]); u.w[1] = pkrtz(x0[2], x0[3]);
    u.w[2] = pkrtz(x1[0], x1[1]); u.w[3] = pkrtz(x1[2], x1[3]);
    ff[s] = u.h;
  }
#pragma unroll
  for (int m = 0; m < 2; ++m){
    f32x4 a = fz;
#pragma unroll
    for (int s = 0; s < 4; ++s)
      a = mfma16(ldg8(fc1p + (m*4+s)*512 + lane*8), ff[s], a);
    f32x4 bv = *(const f32x4*)(fb + m*16 + q*4);
    unsigned u0 = pkrtz(fmaxf(a[0]+bv[0],0.f), fmaxf(a[1]+bv[1],0.f));
    unsigned u1 = pkrtz(fmaxf(a[2]+bv[2],0.f), fmaxf(a[3]+bv[3],0.f));
    *(unsigned*)(f1G + det*32 + q*8 + m*4)     = u0;
    *(unsigned*)(f1G + det*32 + q*8 + m*4 + 2) = u1;
  }
}

// ---- one graph block: edge MLP + segment max + post MLPs + residual + next f1 ----
// grid 512 x 256 (round-3 regime): 16 dets/WG, 4 dets/wave, weights in VGPRs.
// The W_c x f1[det] product is et-invariant (Bc broadcast): computed once per det
// and folded into the pw1 bias (saves 12 of 48 pw1 MFMAs per det).
__global__ __launch_bounds__(256) void kBlk(const _Float16* pfp, const _Float16* f1in,
    _Float16* f1out, const int* nI, const _Float16* pw1p, const _Float16* pw2p,
    const _Float16* post0p, const _Float16* post1p, const _Float16* outp, const _Float16* fc1pn,
    const float* bb1, const float* bb2, const float* pb0, const float* pb1, const float* ob,
    const float* fbn, const float* fin, float* fout, int doF1){
  __shared__ __align__(16) _Float16 poolS[1024];  // [2 halves][16 dets][32 halfs]
  int tid = threadIdx.x, lane = tid & 63, wave = tid >> 6;
  int q = lane >> 4, e = lane & 15;
  int base = blockIdx.x * 16;
  const f32x4 fz = {0.f, 0.f, 0.f, 0.f};

  half8 aW1[4][3], aW2[4][2];
  f32x4 b1v[4];
  unsigned b2p[8];   // pw2 bias, packed to match cvtpack slot order
#pragma unroll
  for (int m = 0; m < 4; ++m){
#pragma unroll
    for (int k = 0; k < 3; ++k) aW1[m][k] = ldg8(pw1p + (m*3+k)*512 + lane*8);
#pragma unroll
    for (int k = 0; k < 2; ++k) aW2[m][k] = ldg8(pw2p + (m*2+k)*512 + lane*8);
    b1v[m] = *(const f32x4*)(bb1 + m*16 + q*4);
    b2p[m*2+0] = pkrtz(bb2[m*16 + q*4 + 0], bb2[m*16 + q*4 + 1]);
    b2p[m*2+1] = pkrtz(bb2[m*16 + q*4 + 2], bb2[m*16 + q*4 + 3]);
  }

  // ---- phase A: edge MLP + packed-f16 pooling (4 dets per wave) ----
  for (int dd = 0; dd < 4; ++dd){
    int d = wave*4 + dd;
    int det = base + d;
    half8 Bc = ldg8(f1in + det*32 + q*8);   // cIdxs == det for every edge of det
    int nn[4];
#pragma unroll
    for (int et = 0; et < 4; ++et) nn[et] = nI[det*64 + et*16 + e];
    half8 Bpf[4], Bn[4];
#pragma unroll
    for (int et = 0; et < 4; ++et){
      Bpf[et] = ldg8(pfp + (det*4+et)*512 + lane*8);
      Bn[et]  = ldg8(f1in + nn[et]*32 + q*8);
    }
    // et-invariant c-contribution, folded into pw1 bias
    f32x4 bcb[4];
#pragma unroll
    for (int m = 0; m < 4; ++m){
      f32x4 dc = mfma16(aW1[m][1], Bc, fz);
#pragma unroll
      for (int r = 0; r < 4; ++r) bcb[m][r] = dc[r] + b1v[m][r];
    }
    unsigned pm[8];
#pragma unroll
    for (int i = 0; i < 8; ++i) pm[i] = 0xFC00FC00u;   // (-inf, -inf)
#pragma unroll
    for (int et = 0; et < 4; ++et){
      f32x4 acc[4];
#pragma unroll
      for (int m = 0; m < 4; ++m){
        acc[m] = mfma16(aW1[m][0], Bpf[et], fz);
        acc[m] = mfma16(aW1[m][2], Bn[et], acc[m]);
      }
      f32x4 r0, r1, r2, r3;
#pragma unroll
      for (int r = 0; r < 4; ++r){
        r0[r] = fmaxf(acc[0][r] + bcb[0][r], 0.f);
        r1[r] = fmaxf(acc[1][r] + bcb[1][r], 0.f);
        r2[r] = fmaxf(acc[2][r] + bcb[2][r], 0.f);
        r3[r] = fmaxf(acc[3][r] + bcb[3][r], 0.f);
      }
      half8 h1a = cvtpack(r0, r1);
      half8 h1b = cvtpack(r2, r3);
      f32x4 a2[4];
#pragma unroll
      for (int m = 0; m < 4; ++m){
        a2[m] = mfma16(aW2[m][0], h1a, fz);
        a2[m] = mfma16(aW2[m][1], h1b, a2[m]);
      }
      // pack raw a2 (bias+relu deferred past the max) and pk-max accumulate
      union { half8 h; unsigned w[4]; } uA, uB;
      uA.h = cvtpack(a2[0], a2[1]);
      uB.h = cvtpack(a2[2], a2[3]);
#pragma unroll
      for (int i = 0; i < 4; ++i){
        pm[i]   = hmax2u(pm[i],   uA.w[i]);
        pm[4+i] = hmax2u(pm[4+i], uB.w[i]);
      }
    }
    // butterfly max over the 16 edge columns (packed)
#pragma unroll
    for (int s = 1; s <= 8; s <<= 1){
#pragma unroll
      for (int i = 0; i < 8; ++i)
        pm[i] = hmax2u(pm[i], __shfl_xor(pm[i], s));
    }
    // deferred bias + relu (packed)
#pragma unroll
    for (int i = 0; i < 8; ++i)
      pm[i] = hmax2u(hadd2u(pm[i], b2p[i]), 0u);
    if (e == 0){
      union { unsigned w[4]; half8 h; } o0, o1;
#pragma unroll
      for (int i = 0; i < 4; ++i){ o0.w[i] = pm[i]; o1.w[i] = pm[4+i]; }
      *(half8*)(poolS + d*32 + q*8)       = o0.h;   // k 0..31
      *(half8*)(poolS + 512 + d*32 + q*8) = o1.h;   // k 32..63
    }
  }
  __syncthreads();

  // ---- phase B: post MLPs + residual + next f1 (16 dets as frag cols) ----
  half8 Bp0 = *(const half8*)(poolS + e*32 + q*8);
  half8 Bp1 = *(const half8*)(poolS + 512 + e*32 + q*8);
  int det = base + e;
  f32x4 t0[4];
#pragma unroll
  for (int m = 0; m < 4; ++m){
    f32x4 a = mfma16(ldg8(post0p + (m*2)*512   + lane*8), Bp0, fz);
    a = mfma16(ldg8(post0p + (m*2+1)*512 + lane*8), Bp1, a);
    f32x4 bv = *(const f32x4*)(pb0 + m*16 + q*4);
#pragma unroll
    for (int r = 0; r < 4; ++r) t0[m][r] = fmaxf(a[r] + bv[r], 0.f);
  }
  half8 p1a = cvtpack(t0[0], t0[1]);
  half8 p1b = cvtpack(t0[2], t0[3]);
#pragma unroll
  for (int m = 0; m < 4; ++m){
    f32x4 a = mfma16(ldg8(post1p + (m*2)*512   + lane*8), p1a, fz);
    a = mfma16(ldg8(post1p + (m*2+1)*512 + lane*8), p1b, a);
    f32x4 bv = *(const f32x4*)(pb1 + m*16 + q*4);
#pragma unroll
    for (int r = 0; r < 4; ++r) t0[m][r] = fmaxf(a[r] + bv[r], 0.f);
  }
  half8 p2a = cvtpack(t0[0], t0[1]);
  half8 p2b = cvtpack(t0[2], t0[3]);
  f32x4 fr[8];
#pragma unroll
  for (int m = 0; m < 8; ++m){
    f32x4 a = mfma16(ldg8(outp + (m*2)*512   + lane*8), p2a, fz);
    a = mfma16(ldg8(outp + (m*2+1)*512 + lane*8), p2b, a);
    f32x4 bv = *(const f32x4*)(ob + m*16 + q*4);
    f32x4 fv = *(const f32x4*)(fin + det*128 + m*16 + q*4);
#pragma unroll
    for (int r = 0; r < 4; ++r) fr[m][r] = fmaxf(fv[r] + a[r] + bv[r], 0.f);
  }
#pragma unroll
  for (int mm = 0; mm < 2; ++mm){
    int m = wave*2 + mm;
    *(f32x4*)(fout + det*128 + m*16 + q*4) = fr[m];
  }
  if (doF1 && wave == 0){
    half8 ff[4];
#pragma unroll
    for (int s = 0; s < 4; ++s) ff[s] = cvtpack(fr[2*s], fr[2*s+1]);
#pragma unroll
    for (int m = 0; m < 2; ++m){
      f32x4 a = fz;
#pragma unroll
      for (int s = 0; s < 4; ++s)
        a = mfma16(ldg8(fc1pn + (m*4+s)*512 + lane*8), ff[s], a);
      f32x4 bv = *(const f32x4*)(fbn + m*16 + q*4);
      unsigned u0 = pkrtz(fmaxf(a[0]+bv[0],0.f), fmaxf(a[1]+bv[1],0.f));
      unsigned u1 = pkrtz(fmaxf(a[2]+bv[2],0.f), fmaxf(a[3]+bv[3],0.f));
      *(unsigned*)(f1out + det*32 + q*8 + m*4)     = u0;
      *(unsigned*)(f1out + det*32 + q*8 + m*4 + 2) = u1;
    }
  }
}

extern "C" void kernel_launch(void* const* d_in, const int* in_sizes, int n_in,
                              void* d_out, int out_size, void* d_ws, size_t ws_size,
                              hipStream_t stream){
  const float* detScores   = (const float*)d_in[0];
  const float* dtBoxes     = (const float*)d_in[1];
  const float* detFeatures = (const float*)d_in[2];
  const int*   cI          = (const int*)d_in[3];
  const int*   nI          = (const int*)d_in[4];
  const float* pwW0 = (const float*)d_in[5];
  const float* pwb0 = (const float*)d_in[6];
  const float* pwW1 = (const float*)d_in[7];
  const float* pwb1 = (const float*)d_in[8];
  const float* pwW2 = (const float*)d_in[9];
  const float* pwb2 = (const float*)d_in[10];
  const float* fc1W = (const float*)d_in[11];
  const float* fc1b = (const float*)d_in[12];
  const float* pw1W = (const float*)d_in[13];
  const float* pw1b = (const float*)d_in[14];
  const float* pw2W = (const float*)d_in[15];
  const float* pw2b = (const float*)d_in[16];
  const float* postW = (const float*)d_in[17];
  const float* postb = (const float*)d_in[18];
  const float* outW  = (const float*)d_in[19];
  const float* outb  = (const float*)d_in[20];

  _Float16* wsh  = (_Float16*)d_ws;
  float*    fbuf = (float*)((char*)d_ws + OFF_FBUF_BYTES);
  _Float16* f1A  = wsh + OFF_F1A;
  _Float16* f1B  = wsh + OFF_F1B;
  _Float16* pfp  = wsh + OFF_PFP;

  kPrep<<<160, 256, 0, stream>>>(pwW0, pwb0, pwW1, pwW2, fc1W, pw1W, pw2W, postW, outW, wsh);
  kF1<<<128, 256, 0, stream>>>(detFeatures, wsh + OFF_FC1P, fc1b, f1A);
  kP<<<2048, 512, 0, stream>>>(detScores, dtBoxes, cI, nI, pwb1, pwb2,
      wsh + OFF_W0P, wsh + OFF_W1P, wsh + OFF_W2P, pfp);

  for (int i = 0; i < 8; ++i){
    int last = (i == 7);
    _Float16* fin1  = (i & 1) ? f1B : f1A;
    _Float16* fout1 = (i & 1) ? f1A : f1B;
    kBlk<<<512, 256, 0, stream>>>(pfp, fin1, fout1, nI,
        wsh + OFF_PW1P + i*6144, wsh + OFF_PW2P + i*4096,
        wsh + OFF_POSTP + i*8192, wsh + OFF_POSTP + i*8192 + 4096, wsh + OFF_OUTP + i*8192,
        wsh + OFF_FC1P + ((i+1) & 7)*4096,
        pw1b + i*64, pw2b + i*64, postb + i*128, postb + i*128 + 64, outb + i*128,
        fc1b + ((i+1) & 7)*32,
        (i == 0) ? detFeatures : fbuf, last ? (float*)d_out : fbuf, last ? 0 : 1);
  }
}

// Round 10
// 283.544 us; speedup vs baseline: 1.5494x; 1.0096x over previous
//
#include <hip/hip_runtime.h>
#include <hip/hip_bf16.h>

typedef _Float16 half8 __attribute__((ext_vector_type(8)));
typedef __fp16 fp16x2 __attribute__((ext_vector_type(2)));
typedef float f32x4 __attribute__((ext_vector_type(4)));

#define N_DETS 8192

// ---- workspace layout (offsets in _Float16 units unless noted) ----
#define OFF_W0P   0          // 16 frags x 512 (k=9 row holds pw_b0)
#define OFF_W1P   8192       // 16x8x512
#define OFF_W2P   73728      // 2x8x512
#define OFF_FC1P  81920      // 8 x (2x4x512)
#define OFF_PW1P  114688     // 8 x (4x3x512)
#define OFF_PW2P  163840     // 8 x (4x2x512)
#define OFF_POSTP 196608     // 8 x 2 x (4x2x512)
#define OFF_OUTP  262144     // 8 x (8x2x512)
#define OFF_F1A   327680     // 8192x32 f16 (pi-frag layout), ping
#define OFF_F1B   589824     // 8192x32 f16, pong
#define OFF_PFP   1114112    // 32768 edge-tiles x 512 (pi-frags of pairFeatures)
#define OFF_FBUF_BYTES 35782656  // f32 [8192][128]

// pi slot map: physical slot (g = lane>>4, j) <-> logical k = ((j>>2)<<4) + g*4 + (j&3)
// Both MFMA operands use the same map, so products pair correctly, and the D-tile
// pair (rows 0..15, 16..31) converts to a B-frag with pure in-lane packing.

__device__ inline f32x4 mfma16(half8 a, half8 b, f32x4 c){
  return __builtin_amdgcn_mfma_f32_16x16x32_f16(a, b, c, 0, 0, 0);
}
__device__ inline half8 ldg8(const _Float16* p){ return *(const half8*)p; }

__device__ inline unsigned pkrtz(float a, float b){
  union { fp16x2 h; unsigned u; } x;
  x.h = __builtin_amdgcn_cvt_pkrtz(a, b);
  return x.u;
}
// packed f16 max/add via direct ISA (avoids hip header overload clashes)
__device__ inline unsigned hmax2u(unsigned a, unsigned b){
  unsigned r;
  asm("v_pk_max_f16 %0, %1, %2" : "=v"(r) : "v"(a), "v"(b));
  return r;
}
__device__ inline unsigned hadd2u(unsigned a, unsigned b){
  unsigned r;
  asm("v_pk_add_f16 %0, %1, %2" : "=v"(r) : "v"(a), "v"(b));
  return r;
}

// D-pair -> B-frag under pi: slots 0-3 = A rows g*4+r, slots 4-7 = B rows 16+g*4+r.
__device__ inline half8 cvtpack(f32x4 A, f32x4 B){
  union { unsigned w[4]; half8 h; } r;
  r.w[0] = pkrtz(A[0], A[1]); r.w[1] = pkrtz(A[2], A[3]);
  r.w[2] = pkrtz(B[0], B[1]); r.w[3] = pkrtz(B[2], B[3]);
  return r.h;
}
// cvtpack + packed bias + relu (deferred epilogue, f16 domain)
__device__ inline half8 cvtpackbr(f32x4 A, f32x4 B, const unsigned* pb){
  union { unsigned w[4]; half8 h; } r;
  r.w[0] = pkrtz(A[0], A[1]); r.w[1] = pkrtz(A[2], A[3]);
  r.w[2] = pkrtz(B[0], B[1]); r.w[3] = pkrtz(B[2], B[3]);
#pragma unroll
  for (int i = 0; i < 4; ++i) r.w[i] = hmax2u(hadd2u(r.w[i], pb[i]), 0u);
  return r.h;
}
// cvtpack + relu only
__device__ inline half8 cvtpackr(f32x4 A, f32x4 B){
  union { unsigned w[4]; half8 h; } r;
  r.w[0] = pkrtz(A[0], A[1]); r.w[1] = pkrtz(A[2], A[3]);
  r.w[2] = pkrtz(B[0], B[1]); r.w[3] = pkrtz(B[2], B[3]);
#pragma unroll
  for (int i = 0; i < 4; ++i) r.w[i] = hmax2u(r.w[i], 0u);
  return r.h;
}

// ---- weight packing in pi order (valid as A-frags of W^T) ----
__device__ inline void packB(const float* W, int Ksrc, int Nn, _Float16* dst, int sig){
  int ns = (Ksrc + 31) >> 5;
  int t = sig / (ns * 64);
  int rem = sig - t * ns * 64;
  int s = rem >> 6;
  int l = rem & 63;
  int col = t * 16 + (l & 15);
  int g = l >> 4;
  half8 v;
#pragma unroll
  for (int j = 0; j < 8; ++j){
    int k = s*32 + ((j>>2)<<4) + g*4 + (j&3);
    v[j] = (_Float16)((k < Ksrc) ? W[k * Nn + col] : 0.f);
  }
  *(half8*)(dst + sig * 8) = v;
}

__device__ inline void packW0(const float* W, const float* bias, _Float16* dst, int sig){
  int t = sig >> 6, l = sig & 63;
  int col = t * 16 + (l & 15);
  int g = l >> 4;
  half8 v;
#pragma unroll
  for (int j = 0; j < 8; ++j){
    int k = ((j>>2)<<4) + g*4 + (j&3);
    float x = 0.f;
    if (k < 9) x = W[k * 256 + col];
    else if (k == 9) x = bias[col];
    v[j] = (_Float16)x;
  }
  *(half8*)(dst + sig * 8) = v;
}

__global__ __launch_bounds__(256) void kPrep(const float* pwW0, const float* pwb0,
    const float* pwW1, const float* pwW2,
    const float* fc1W, const float* pw1W, const float* pw2W, const float* postW, const float* outW,
    _Float16* wsh){
  int sig = blockIdx.x * 256 + threadIdx.x;
  if (sig < 1024){ packW0(pwW0, pwb0, wsh + OFF_W0P, sig); return; }
  sig -= 1024;
  if (sig < 8192){ packB(pwW1, 256, 256, wsh + OFF_W1P, sig); return; }
  sig -= 8192;
  if (sig < 1024){ packB(pwW2, 256, 32, wsh + OFF_W2P, sig); return; }
  sig -= 1024;
  int i = sig / 3840;
  int q = sig - i * 3840;
  if (q < 512){ packB(fc1W + i*4096, 128, 32, wsh + OFF_FC1P + i*4096, q); return; }
  q -= 512;
  if (q < 768){ packB(pw1W + i*6144, 96, 64, wsh + OFF_PW1P + i*6144, q); return; }
  q -= 768;
  if (q < 512){ packB(pw2W + i*4096, 64, 64, wsh + OFF_PW2P + i*4096, q); return; }
  q -= 512;
  if (q < 512){ packB(postW + i*8192, 64, 64, wsh + OFF_POSTP + i*8192, q); return; }
  q -= 512;
  if (q < 512){ packB(postW + i*8192 + 4096, 64, 64, wsh + OFF_POSTP + i*8192 + 4096, q); return; }
  q -= 512;
  packB(outW + i*8192, 64, 128, wsh + OFF_OUTP + i*8192, q);
}

// ---- fused pairwise MLP: 128 edges/WG (256 thr, 4 waves), 2 e-tiles/wave ----
__global__ __launch_bounds__(256) void kP(const float* scores, const float* boxes,
    const int* cI, const int* nI, const float* b1, const float* b2,
    const _Float16* W0p, const _Float16* W1p, const _Float16* W2p, _Float16* pfp){
  __shared__ __align__(16) _Float16 sbuf[2][8192];
  __shared__ __align__(16) _Float16 rawp[4096];
  int tid = threadIdx.x;
  int lane = tid & 63, wave = tid >> 6;
  const f32x4 fz = {0.f, 0.f, 0.f, 0.f};

  // prologue: issue W0 + slice0 loads (reg-staged), zero raw buffer
  half8 w0ld[4], s0ld[4];
#pragma unroll
  for (int it = 0; it < 4; ++it){
    w0ld[it] = ldg8(W0p + it*2048 + tid*8);
    s0ld[it] = ldg8(W1p + it*2048 + tid*8);
  }
  {
    half8 z = {0,0,0,0,0,0,0,0};
#pragma unroll
    for (int it = 0; it < 2; ++it) *(half8*)(rawp + it*2048 + tid*8) = z;
  }
  __syncthreads();
  if (tid < 128){
    int e = blockIdx.x*128 + tid;
    int c = cI[e], n = nI[e];
    float cx1 = boxes[c*4+0], cy1 = boxes[c*4+1], cx2 = boxes[c*4+2], cy2 = boxes[c*4+3];
    float nx1 = boxes[n*4+0], ny1 = boxes[n*4+1], nx2 = boxes[n*4+2], ny2 = boxes[n*4+3];
    float cw = cx2-cx1, ch = cy2-cy1, nw = nx2-nx1, nh = ny2-ny1;
    float ca = cw*ch, na = nw*nh;
    float ix = fmaxf(fminf(cx2,nx2) - fmaxf(cx1,nx1), 0.f);
    float iy = fmaxf(fminf(cy2,ny2) - fmaxf(cy1,ny1), 0.f);
    float inter = ix*iy;
    float iou = inter / (ca + na - inter);
    float cs = (cw + ch) * 0.5f;
    float xd = (nx1 + nw*0.5f) - (cx1 + cw*0.5f);
    float yd = (ny1 + nh*0.5f) - (cy1 + ch*0.5f);
    float l2 = sqrtf(xd*xd + yd*yd) / cs;
    float wd = log2f(nw/cw), hd = log2f(nh/ch);
    float ad = log2f(nw/nh) - log2f(cw/ch);
    float rv[10] = {scores[c], scores[n], iou, xd/cs, yd/cs, l2, wd, hd, ad, 1.0f};
    int base = (tid >> 4) * 512;   // e-tile region
    int r = tid & 15;
#pragma unroll
    for (int k = 0; k < 10; ++k)
      rawp[base + (((k>>2)&3)*16 + r)*8 + (k&3)] = (_Float16)rv[k];   // pi position
  }
#pragma unroll
  for (int it = 0; it < 4; ++it){
    *(half8*)(&sbuf[0][0] + it*2048 + tid*8) = w0ld[it];
    *(half8*)(&sbuf[1][0] + it*2048 + tid*8) = s0ld[it];
  }
  __syncthreads();

  // L0: h0T = W0T * rawT  (bias folded via raw[9]=1; relu in packed f16)
  half8 h0f[2][8];
#pragma unroll
  for (int et = 0; et < 2; ++et){
    half8 braw = *(const half8*)(rawp + ((wave*2+et)*64 + lane)*8);
#pragma unroll
    for (int mp = 0; mp < 8; ++mp){
      f32x4 a = mfma16(*(const half8*)(&sbuf[0][0] + (2*mp)*512   + lane*8), braw, fz);
      f32x4 b = mfma16(*(const half8*)(&sbuf[0][0] + (2*mp+1)*512 + lane*8), braw, fz);
      h0f[et][mp] = cvtpackr(a, b);
    }
  }
  __syncthreads();   // protect sbuf[0] before slice1 is written into it

  // L1 + fused L2: loop over 8 output m-pairs of h1, double-buffered slices
  int q = lane >> 4;
  f32x4 apf[2][2];
  apf[0][0] = fz; apf[0][1] = fz; apf[1][0] = fz; apf[1][1] = fz;
  for (int mp = 0; mp < 8; ++mp){
    const _Float16* cur = &sbuf[(mp+1)&1][0];
    half8 stg[4];
    if (mp < 7){
#pragma unroll
      for (int it = 0; it < 4; ++it)
        stg[it] = ldg8(W1p + (mp+1)*8192 + it*2048 + tid*8);
    }
    f32x4 acc[2][2];
    acc[0][0] = fz; acc[0][1] = fz; acc[1][0] = fz; acc[1][1] = fz;
#pragma unroll
    for (int s = 0; s < 8; ++s){
      half8 A0 = *(const half8*)(cur + s*512       + lane*8);
      half8 A1 = *(const half8*)(cur + (8+s)*512   + lane*8);
#pragma unroll
      for (int et = 0; et < 2; ++et){
        acc[et][0] = mfma16(A0, h0f[et][s], acc[et][0]);
        acc[et][1] = mfma16(A1, h0f[et][s], acc[et][1]);
      }
    }
    // packed bias for this mp (shared by both et)
    unsigned pb[4];
    pb[0] = pkrtz(b1[mp*32 + q*4 + 0], b1[mp*32 + q*4 + 1]);
    pb[1] = pkrtz(b1[mp*32 + q*4 + 2], b1[mp*32 + q*4 + 3]);
    pb[2] = pkrtz(b1[mp*32 + 16 + q*4 + 0], b1[mp*32 + 16 + q*4 + 1]);
    pb[3] = pkrtz(b1[mp*32 + 16 + q*4 + 2], b1[mp*32 + 16 + q*4 + 3]);
    half8 w2a = ldg8(W2p + mp*512 + lane*8);
    half8 w2b = ldg8(W2p + (8+mp)*512 + lane*8);
#pragma unroll
    for (int et = 0; et < 2; ++et){
      half8 h1f = cvtpackbr(acc[et][0], acc[et][1], pb);
      apf[et][0] = mfma16(w2a, h1f, apf[et][0]);
      apf[et][1] = mfma16(w2b, h1f, apf[et][1]);
    }
    if (mp < 7){
      _Float16* nxt = &sbuf[mp&1][0];
#pragma unroll
      for (int it = 0; it < 4; ++it)
        *(half8*)(nxt + it*2048 + tid*8) = stg[it];
    }
    __syncthreads();
  }
  // epilogue: pf = relu(pfT + b2) in packed f16 -> store
  unsigned pc[4];
  pc[0] = pkrtz(b2[q*4 + 0], b2[q*4 + 1]);
  pc[1] = pkrtz(b2[q*4 + 2], b2[q*4 + 3]);
  pc[2] = pkrtz(b2[16 + q*4 + 0], b2[16 + q*4 + 1]);
  pc[3] = pkrtz(b2[16 + q*4 + 2], b2[16 + q*4 + 3]);
#pragma unroll
  for (int et = 0; et < 2; ++et){
    half8 pf = cvtpackbr(apf[et][0], apf[et][1], pc);
    *(half8*)(pfp + (blockIdx.x*8 + wave*2 + et)*512 + lane*8) = pf;
  }
}

// ---- initial f1 (transposed), 16 dets per wave, 4 waves/WG ----
__global__ __launch_bounds__(256) void kF1(const float* detF, const _Float16* fc1p,
    const float* fb, _Float16* f1G){
  int lane = threadIdx.x & 63, wave = threadIdx.x >> 6;
  int q = lane >> 4, e = lane & 15;
  int det = (blockIdx.x * 4 + wave) * 16 + e;
  const f32x4 fz = {0.f, 0.f, 0.f, 0.f};
  half8 ff[4];
#pragma unroll
  for (int s = 0; s < 4; ++s){
    const float* p = detF + det*128 + s*32 + q*4;
    f32x4 x0 = *(const f32x4*)(p);
    f32x4 x1 = *(const f32x4*)(p + 16);
    union { unsigned w[4]; half8 h; } u;
    u.w[0] = pkrtz(x0[0], x0[1]); u.w[1] = pkrtz(x0[2], x0[3]);
    u.w[2] = pkrtz(x1[0], x1[1]); u.w[3] = pkrtz(x1[2], x1[3]);
    ff[s] = u.h;
  }
#pragma unroll
  for (int m = 0; m < 2; ++m){
    f32x4 a = fz;
#pragma unroll
    for (int s = 0; s < 4; ++s)
      a = mfma16(ldg8(fc1p + (m*4+s)*512 + lane*8), ff[s], a);
    f32x4 bv = *(const f32x4*)(fb + m*16 + q*4);
    unsigned u0 = pkrtz(fmaxf(a[0]+bv[0],0.f), fmaxf(a[1]+bv[1],0.f));
    unsigned u1 = pkrtz(fmaxf(a[2]+bv[2],0.f), fmaxf(a[3]+bv[3],0.f));
    *(unsigned*)(f1G + det*32 + q*8 + m*4)     = u0;
    *(unsigned*)(f1G + det*32 + q*8 + m*4 + 2) = u1;
  }
}

// ---- one graph block: edge MLP + segment max + post MLPs + residual + next f1 ----
// grid 512 x 256: 16 dets/WG, 4 dets/wave, weights in VGPRs.
// The W_c x f1[det] product is et-invariant (Bc broadcast): computed once per det
// and folded into the pw1 bias (saves 12 of 48 pw1 MFMAs per det).
__global__ __launch_bounds__(256) void kBlk(const _Float16* pfp, const _Float16* f1in,
    _Float16* f1out, const int* nI, const _Float16* pw1p, const _Float16* pw2p,
    const _Float16* post0p, const _Float16* post1p, const _Float16* outp, const _Float16* fc1pn,
    const float* bb1, const float* bb2, const float* pb0, const float* pb1, const float* ob,
    const float* fbn, const float* fin, float* fout, int doF1){
  __shared__ __align__(16) _Float16 poolS[1024];  // [2 halves][16 dets][32 halfs]
  int tid = threadIdx.x, lane = tid & 63, wave = tid >> 6;
  int q = lane >> 4, e = lane & 15;
  int base = blockIdx.x * 16;
  const f32x4 fz = {0.f, 0.f, 0.f, 0.f};

  half8 aW1[4][3], aW2[4][2];
  f32x4 b1v[4];
  unsigned b2p[8];   // pw2 bias, packed to match cvtpack slot order
#pragma unroll
  for (int m = 0; m < 4; ++m){
#pragma unroll
    for (int k = 0; k < 3; ++k) aW1[m][k] = ldg8(pw1p + (m*3+k)*512 + lane*8);
#pragma unroll
    for (int k = 0; k < 2; ++k) aW2[m][k] = ldg8(pw2p + (m*2+k)*512 + lane*8);
    b1v[m] = *(const f32x4*)(bb1 + m*16 + q*4);
    b2p[m*2+0] = pkrtz(bb2[m*16 + q*4 + 0], bb2[m*16 + q*4 + 1]);
    b2p[m*2+1] = pkrtz(bb2[m*16 + q*4 + 2], bb2[m*16 + q*4 + 3]);
  }

  // ---- phase A: edge MLP + packed-f16 pooling (4 dets per wave) ----
  for (int dd = 0; dd < 4; ++dd){
    int d = wave*4 + dd;
    int det = base + d;
    half8 Bc = ldg8(f1in + det*32 + q*8);   // cIdxs == det for every edge of det
    int nn[4];
#pragma unroll
    for (int et = 0; et < 4; ++et) nn[et] = nI[det*64 + et*16 + e];
    half8 Bpf[4], Bn[4];
#pragma unroll
    for (int et = 0; et < 4; ++et){
      Bpf[et] = ldg8(pfp + (det*4+et)*512 + lane*8);
      Bn[et]  = ldg8(f1in + nn[et]*32 + q*8);
    }
    // et-invariant c-contribution, folded into pw1 bias
    f32x4 bcb[4];
#pragma unroll
    for (int m = 0; m < 4; ++m){
      f32x4 dc = mfma16(aW1[m][1], Bc, fz);
#pragma unroll
      for (int r = 0; r < 4; ++r) bcb[m][r] = dc[r] + b1v[m][r];
    }
    unsigned pm[8];
#pragma unroll
    for (int i = 0; i < 8; ++i) pm[i] = 0xFC00FC00u;   // (-inf, -inf)
#pragma unroll
    for (int et = 0; et < 4; ++et){
      f32x4 acc[4];
#pragma unroll
      for (int m = 0; m < 4; ++m){
        acc[m] = mfma16(aW1[m][0], Bpf[et], fz);
        acc[m] = mfma16(aW1[m][2], Bn[et], acc[m]);
      }
      f32x4 r0, r1, r2, r3;
#pragma unroll
      for (int r = 0; r < 4; ++r){
        r0[r] = fmaxf(acc[0][r] + bcb[0][r], 0.f);
        r1[r] = fmaxf(acc[1][r] + bcb[1][r], 0.f);
        r2[r] = fmaxf(acc[2][r] + bcb[2][r], 0.f);
        r3[r] = fmaxf(acc[3][r] + bcb[3][r], 0.f);
      }
      half8 h1a = cvtpack(r0, r1);
      half8 h1b = cvtpack(r2, r3);
      f32x4 a2[4];
#pragma unroll
      for (int m = 0; m < 4; ++m){
        a2[m] = mfma16(aW2[m][0], h1a, fz);
        a2[m] = mfma16(aW2[m][1], h1b, a2[m]);
      }
      // pack raw a2 (bias+relu deferred past the max) and pk-max accumulate
      union { half8 h; unsigned w[4]; } uA, uB;
      uA.h = cvtpack(a2[0], a2[1]);
      uB.h = cvtpack(a2[2], a2[3]);
#pragma unroll
      for (int i = 0; i < 4; ++i){
        pm[i]   = hmax2u(pm[i],   uA.w[i]);
        pm[4+i] = hmax2u(pm[4+i], uB.w[i]);
      }
    }
    // butterfly max over the 16 edge columns (packed)
#pragma unroll
    for (int s = 1; s <= 8; s <<= 1){
#pragma unroll
      for (int i = 0; i < 8; ++i)
        pm[i] = hmax2u(pm[i], __shfl_xor(pm[i], s));
    }
    // deferred bias + relu (packed)
#pragma unroll
    for (int i = 0; i < 8; ++i)
      pm[i] = hmax2u(hadd2u(pm[i], b2p[i]), 0u);
    if (e == 0){
      union { unsigned w[4]; half8 h; } o0, o1;
#pragma unroll
      for (int i = 0; i < 4; ++i){ o0.w[i] = pm[i]; o1.w[i] = pm[4+i]; }
      *(half8*)(poolS + d*32 + q*8)       = o0.h;   // k 0..31
      *(half8*)(poolS + 512 + d*32 + q*8) = o1.h;   // k 32..63
    }
  }
  __syncthreads();

  // ---- phase B: post MLPs + residual + next f1 (16 dets as frag cols) ----
  half8 Bp0 = *(const half8*)(poolS + e*32 + q*8);
  half8 Bp1 = *(const half8*)(poolS + 512 + e*32 + q*8);
  int det = base + e;
  f32x4 t0[4];
#pragma unroll
  for (int m = 0; m < 4; ++m){
    f32x4 a = mfma16(ldg8(post0p + (m*2)*512   + lane*8), Bp0, fz);
    a = mfma16(ldg8(post0p + (m*2+1)*512 + lane*8), Bp1, a);
    f32x4 bv = *(const f32x4*)(pb0 + m*16 + q*4);
#pragma unroll
    for (int r = 0; r < 4; ++r) t0[m][r] = fmaxf(a[r] + bv[r], 0.f);
  }
  half8 p1a = cvtpack(t0[0], t0[1]);
  half8 p1b = cvtpack(t0[2], t0[3]);
#pragma unroll
  for (int m = 0; m < 4; ++m){
    f32x4 a = mfma16(ldg8(post1p + (m*2)*512   + lane*8), p1a, fz);
    a = mfma16(ldg8(post1p + (m*2+1)*512 + lane*8), p1b, a);
    f32x4 bv = *(const f32x4*)(pb1 + m*16 + q*4);
#pragma unroll
    for (int r = 0; r < 4; ++r) t0[m][r] = fmaxf(a[r] + bv[r], 0.f);
  }
  half8 p2a = cvtpack(t0[0], t0[1]);
  half8 p2b = cvtpack(t0[2], t0[3]);
  f32x4 fr[8];
#pragma unroll
  for (int m = 0; m < 8; ++m){
    f32x4 a = mfma16(ldg8(outp + (m*2)*512   + lane*8), p2a, fz);
    a = mfma16(ldg8(outp + (m*2+1)*512 + lane*8), p2b, a);
    f32x4 bv = *(const f32x4*)(ob + m*16 + q*4);
    f32x4 fv = *(const f32x4*)(fin + det*128 + m*16 + q*4);
#pragma unroll
    for (int r = 0; r < 4; ++r) fr[m][r] = fmaxf(fv[r] + a[r] + bv[r], 0.f);
  }
#pragma unroll
  for (int mm = 0; mm < 2; ++mm){
    int m = wave*2 + mm;
    *(f32x4*)(fout + det*128 + m*16 + q*4) = fr[m];
  }
  if (doF1 && wave == 0){
    half8 ff[4];
#pragma unroll
    for (int s = 0; s < 4; ++s) ff[s] = cvtpack(fr[2*s], fr[2*s+1]);
#pragma unroll
    for (int m = 0; m < 2; ++m){
      f32x4 a = fz;
#pragma unroll
      for (int s = 0; s < 4; ++s)
        a = mfma16(ldg8(fc1pn + (m*4+s)*512 + lane*8), ff[s], a);
      f32x4 bv = *(const f32x4*)(fbn + m*16 + q*4);
      unsigned u0 = pkrtz(fmaxf(a[0]+bv[0],0.f), fmaxf(a[1]+bv[1],0.f));
      unsigned u1 = pkrtz(fmaxf(a[2]+bv[2],0.f), fmaxf(a[3]+bv[3],0.f));
      *(unsigned*)(f1out + det*32 + q*8 + m*4)     = u0;
      *(unsigned*)(f1out + det*32 + q*8 + m*4 + 2) = u1;
    }
  }
}

extern "C" void kernel_launch(void* const* d_in, const int* in_sizes, int n_in,
                              void* d_out, int out_size, void* d_ws, size_t ws_size,
                              hipStream_t stream){
  const float* detScores   = (const float*)d_in[0];
  const float* dtBoxes     = (const float*)d_in[1];
  const float* detFeatures = (const float*)d_in[2];
  const int*   cI          = (const int*)d_in[3];
  const int*   nI          = (const int*)d_in[4];
  const float* pwW0 = (const float*)d_in[5];
  const float* pwb0 = (const float*)d_in[6];
  const float* pwW1 = (const float*)d_in[7];
  const float* pwb1 = (const float*)d_in[8];
  const float* pwW2 = (const float*)d_in[9];
  const float* pwb2 = (const float*)d_in[10];
  const float* fc1W = (const float*)d_in[11];
  const float* fc1b = (const float*)d_in[12];
  const float* pw1W = (const float*)d_in[13];
  const float* pw1b = (const float*)d_in[14];
  const float* pw2W = (const float*)d_in[15];
  const float* pw2b = (const float*)d_in[16];
  const float* postW = (const float*)d_in[17];
  const float* postb = (const float*)d_in[18];
  const float* outW  = (const float*)d_in[19];
  const float* outb  = (const float*)d_in[20];

  _Float16* wsh  = (_Float16*)d_ws;
  float*    fbuf = (float*)((char*)d_ws + OFF_FBUF_BYTES);
  _Float16* f1A  = wsh + OFF_F1A;
  _Float16* f1B  = wsh + OFF_F1B;
  _Float16* pfp  = wsh + OFF_PFP;

  kPrep<<<160, 256, 0, stream>>>(pwW0, pwb0, pwW1, pwW2, fc1W, pw1W, pw2W, postW, outW, wsh);
  kF1<<<128, 256, 0, stream>>>(detFeatures, wsh + OFF_FC1P, fc1b, f1A);
  kP<<<4096, 256, 0, stream>>>(detScores, dtBoxes, cI, nI, pwb1, pwb2,
      wsh + OFF_W0P, wsh + OFF_W1P, wsh + OFF_W2P, pfp);

  for (int i = 0; i < 8; ++i){
    int last = (i == 7);
    _Float16* fin1  = (i & 1) ? f1B : f1A;
    _Float16* fout1 = (i & 1) ? f1A : f1B;
    kBlk<<<512, 256, 0, stream>>>(pfp, fin1, fout1, nI,
        wsh + OFF_PW1P + i*6144, wsh + OFF_PW2P + i*4096,
        wsh + OFF_POSTP + i*8192, wsh + OFF_POSTP + i*8192 + 4096, wsh + OFF_OUTP + i*8192,
        wsh + OFF_FC1P + ((i+1) & 7)*4096,
        pw1b + i*64, pw2b + i*64, postb + i*128, postb + i*128 + 64, outb + i*128,
        fc1b + ((i+1) & 7)*32,
        (i == 0) ? detFeatures : fbuf, last ? (float*)d_out : fbuf, last ? 0 : 1);
  }
}

// Round 11
// 241.912 us; speedup vs baseline: 1.8161x; 1.1721x over previous
//
#include <hip/hip_runtime.h>
#include <hip/hip_bf16.h>

typedef _Float16 half8 __attribute__((ext_vector_type(8)));
typedef __fp16 fp16x2 __attribute__((ext_vector_type(2)));
typedef float f32x4 __attribute__((ext_vector_type(4)));

#define N_DETS 8192

// ---- workspace layout (offsets in _Float16 units unless noted) ----
#define OFF_W0P   0          // 16 frags x 512 (k=9 row holds pw_b0)
#define OFF_W1P   8192       // 16x8x512
#define OFF_W2P   73728      // 2x8x512
#define OFF_FC1P  81920      // 8 x (2x4x512)
#define OFF_PW1P  114688     // 8 x (4x3x512)
#define OFF_PW2P  163840     // 8 x (4x2x512)
#define OFF_POSTP 196608     // 8 x 2 x (4x2x512)
#define OFF_OUTP  262144     // 8 x (8x2x512)
#define OFF_F1A   327680     // 8192x32 f16 (pi-frag layout), ping
#define OFF_F1B   589824     // 8192x32 f16, pong
#define OFF_PFP   1114112    // 32768 edge-tiles x 512 (pi-frags of pairFeatures)
#define OFF_FBUF_BYTES 35782656  // f32 [8192][128]

// pi slot map: physical slot (g = lane>>4, j) <-> logical k = ((j>>2)<<4) + g*4 + (j&3)
// Both MFMA operands use the same map, so products pair correctly, and the D-tile
// pair (rows 0..15, 16..31) converts to a B-frag with pure in-lane packing.

__device__ inline f32x4 mfma16(half8 a, half8 b, f32x4 c){
  return __builtin_amdgcn_mfma_f32_16x16x32_f16(a, b, c, 0, 0, 0);
}
__device__ inline half8 ldg8(const _Float16* p){ return *(const half8*)p; }

__device__ inline unsigned pkrtz(float a, float b){
  union { fp16x2 h; unsigned u; } x;
  x.h = __builtin_amdgcn_cvt_pkrtz(a, b);
  return x.u;
}
// packed f16 max/add via direct ISA (avoids hip header overload clashes)
__device__ inline unsigned hmax2u(unsigned a, unsigned b){
  unsigned r;
  asm("v_pk_max_f16 %0, %1, %2" : "=v"(r) : "v"(a), "v"(b));
  return r;
}
__device__ inline unsigned hadd2u(unsigned a, unsigned b){
  unsigned r;
  asm("v_pk_add_f16 %0, %1, %2" : "=v"(r) : "v"(a), "v"(b));
  return r;
}

// D-pair -> B-frag under pi: slots 0-3 = A rows g*4+r, slots 4-7 = B rows 16+g*4+r.
__device__ inline half8 cvtpack(f32x4 A, f32x4 B){
  union { unsigned w[4]; half8 h; } r;
  r.w[0] = pkrtz(A[0], A[1]); r.w[1] = pkrtz(A[2], A[3]);
  r.w[2] = pkrtz(B[0], B[1]); r.w[3] = pkrtz(B[2], B[3]);
  return r.h;
}
// cvtpack + packed bias + relu (deferred epilogue, f16 domain)
__device__ inline half8 cvtpackbr(f32x4 A, f32x4 B, const unsigned* pb){
  union { unsigned w[4]; half8 h; } r;
  r.w[0] = pkrtz(A[0], A[1]); r.w[1] = pkrtz(A[2], A[3]);
  r.w[2] = pkrtz(B[0], B[1]); r.w[3] = pkrtz(B[2], B[3]);
#pragma unroll
  for (int i = 0; i < 4; ++i) r.w[i] = hmax2u(hadd2u(r.w[i], pb[i]), 0u);
  return r.h;
}
// cvtpack + relu only
__device__ inline half8 cvtpackr(f32x4 A, f32x4 B){
  union { unsigned w[4]; half8 h; } r;
  r.w[0] = pkrtz(A[0], A[1]); r.w[1] = pkrtz(A[2], A[3]);
  r.w[2] = pkrtz(B[0], B[1]); r.w[3] = pkrtz(B[2], B[3]);
#pragma unroll
  for (int i = 0; i < 4; ++i) r.w[i] = hmax2u(r.w[i], 0u);
  return r.h;
}

// ---- weight packing in pi order (valid as A-frags of W^T) ----
__device__ inline void packB(const float* W, int Ksrc, int Nn, _Float16* dst, int sig){
  int ns = (Ksrc + 31) >> 5;
  int t = sig / (ns * 64);
  int rem = sig - t * ns * 64;
  int s = rem >> 6;
  int l = rem & 63;
  int col = t * 16 + (l & 15);
  int g = l >> 4;
  half8 v;
#pragma unroll
  for (int j = 0; j < 8; ++j){
    int k = s*32 + ((j>>2)<<4) + g*4 + (j&3);
    v[j] = (_Float16)((k < Ksrc) ? W[k * Nn + col] : 0.f);
  }
  *(half8*)(dst + sig * 8) = v;
}

__device__ inline void packW0(const float* W, const float* bias, _Float16* dst, int sig){
  int t = sig >> 6, l = sig & 63;
  int col = t * 16 + (l & 15);
  int g = l >> 4;
  half8 v;
#pragma unroll
  for (int j = 0; j < 8; ++j){
    int k = ((j>>2)<<4) + g*4 + (j&3);
    float x = 0.f;
    if (k < 9) x = W[k * 256 + col];
    else if (k == 9) x = bias[col];
    v[j] = (_Float16)x;
  }
  *(half8*)(dst + sig * 8) = v;
}

__global__ __launch_bounds__(256) void kPrep(const float* pwW0, const float* pwb0,
    const float* pwW1, const float* pwW2,
    const float* fc1W, const float* pw1W, const float* pw2W, const float* postW, const float* outW,
    _Float16* wsh){
  int sig = blockIdx.x * 256 + threadIdx.x;
  if (sig < 1024){ packW0(pwW0, pwb0, wsh + OFF_W0P, sig); return; }
  sig -= 1024;
  if (sig < 8192){ packB(pwW1, 256, 256, wsh + OFF_W1P, sig); return; }
  sig -= 8192;
  if (sig < 1024){ packB(pwW2, 256, 32, wsh + OFF_W2P, sig); return; }
  sig -= 1024;
  int i = sig / 3840;
  int q = sig - i * 3840;
  if (q < 512){ packB(fc1W + i*4096, 128, 32, wsh + OFF_FC1P + i*4096, q); return; }
  q -= 512;
  if (q < 768){ packB(pw1W + i*6144, 96, 64, wsh + OFF_PW1P + i*6144, q); return; }
  q -= 768;
  if (q < 512){ packB(pw2W + i*4096, 64, 64, wsh + OFF_PW2P + i*4096, q); return; }
  q -= 512;
  if (q < 512){ packB(postW + i*8192, 64, 64, wsh + OFF_POSTP + i*8192, q); return; }
  q -= 512;
  if (q < 512){ packB(postW + i*8192 + 4096, 64, 64, wsh + OFF_POSTP + i*8192 + 4096, q); return; }
  q -= 512;
  packB(outW + i*8192, 64, 128, wsh + OFF_OUTP + i*8192, q);
}

// ---- fused pairwise MLP: 256 edges/WG (256 thr, 4 waves), 4 e-tiles/wave ----
// ET=4 amortizes LDS A-frag reads, barriers, bias/W2 loads over 2x edges and
// provides more independent MFMA between dependent epilogue chains.
__global__ __launch_bounds__(256, 2) void kP(const float* scores, const float* boxes,
    const int* cI, const int* nI, const float* b1, const float* b2,
    const _Float16* W0p, const _Float16* W1p, const _Float16* W2p, _Float16* pfp){
  __shared__ __align__(16) _Float16 sbuf[2][8192];
  __shared__ __align__(16) _Float16 rawp[8192];
  int tid = threadIdx.x;
  int lane = tid & 63, wave = tid >> 6;
  const f32x4 fz = {0.f, 0.f, 0.f, 0.f};

  // prologue: issue W0 + slice0 loads (reg-staged), zero raw buffer
  half8 w0ld[4], s0ld[4];
#pragma unroll
  for (int it = 0; it < 4; ++it){
    w0ld[it] = ldg8(W0p + it*2048 + tid*8);
    s0ld[it] = ldg8(W1p + it*2048 + tid*8);
  }
  {
    half8 z = {0,0,0,0,0,0,0,0};
#pragma unroll
    for (int it = 0; it < 4; ++it) *(half8*)(rawp + it*2048 + tid*8) = z;
  }
  __syncthreads();
  {
    int e = blockIdx.x*256 + tid;
    int c = cI[e], n = nI[e];
    float cx1 = boxes[c*4+0], cy1 = boxes[c*4+1], cx2 = boxes[c*4+2], cy2 = boxes[c*4+3];
    float nx1 = boxes[n*4+0], ny1 = boxes[n*4+1], nx2 = boxes[n*4+2], ny2 = boxes[n*4+3];
    float cw = cx2-cx1, ch = cy2-cy1, nw = nx2-nx1, nh = ny2-ny1;
    float ca = cw*ch, na = nw*nh;
    float ix = fmaxf(fminf(cx2,nx2) - fmaxf(cx1,nx1), 0.f);
    float iy = fmaxf(fminf(cy2,ny2) - fmaxf(cy1,ny1), 0.f);
    float inter = ix*iy;
    float iou = inter / (ca + na - inter);
    float cs = (cw + ch) * 0.5f;
    float xd = (nx1 + nw*0.5f) - (cx1 + cw*0.5f);
    float yd = (ny1 + nh*0.5f) - (cy1 + ch*0.5f);
    float l2 = sqrtf(xd*xd + yd*yd) / cs;
    float wd = log2f(nw/cw), hd = log2f(nh/ch);
    float ad = log2f(nw/nh) - log2f(cw/ch);
    float rv[10] = {scores[c], scores[n], iou, xd/cs, yd/cs, l2, wd, hd, ad, 1.0f};
    int base = (tid >> 4) * 512;   // e-tile region (16 tiles/WG)
    int r = tid & 15;
#pragma unroll
    for (int k = 0; k < 10; ++k)
      rawp[base + (((k>>2)&3)*16 + r)*8 + (k&3)] = (_Float16)rv[k];   // pi position
  }
#pragma unroll
  for (int it = 0; it < 4; ++it){
    *(half8*)(&sbuf[0][0] + it*2048 + tid*8) = w0ld[it];
    *(half8*)(&sbuf[1][0] + it*2048 + tid*8) = s0ld[it];
  }
  __syncthreads();

  // L0: h0T = W0T * rawT  (bias folded via raw[9]=1; relu in packed f16)
  half8 h0f[4][8];
  {
    half8 braw[4];
#pragma unroll
    for (int et = 0; et < 4; ++et)
      braw[et] = *(const half8*)(rawp + ((wave*4+et)*64 + lane)*8);
#pragma unroll
    for (int mp = 0; mp < 8; ++mp){
      half8 A0 = *(const half8*)(&sbuf[0][0] + (2*mp)*512   + lane*8);
      half8 A1 = *(const half8*)(&sbuf[0][0] + (2*mp+1)*512 + lane*8);
#pragma unroll
      for (int et = 0; et < 4; ++et){
        f32x4 a = mfma16(A0, braw[et], fz);
        f32x4 b = mfma16(A1, braw[et], fz);
        h0f[et][mp] = cvtpackr(a, b);
      }
    }
  }
  __syncthreads();   // protect sbuf[0] before slice1 is written into it

  // L1 + fused L2: loop over 8 output m-pairs of h1, double-buffered slices
  int q = lane >> 4;
  f32x4 apf[4][2];
#pragma unroll
  for (int et = 0; et < 4; ++et){ apf[et][0] = fz; apf[et][1] = fz; }
  for (int mp = 0; mp < 8; ++mp){
    const _Float16* cur = &sbuf[(mp+1)&1][0];
    half8 stg[4];
    if (mp < 7){
#pragma unroll
      for (int it = 0; it < 4; ++it)
        stg[it] = ldg8(W1p + (mp+1)*8192 + it*2048 + tid*8);
    }
    f32x4 acc[4][2];
#pragma unroll
    for (int et = 0; et < 4; ++et){ acc[et][0] = fz; acc[et][1] = fz; }
#pragma unroll
    for (int s = 0; s < 8; ++s){
      half8 A0 = *(const half8*)(cur + s*512       + lane*8);
      half8 A1 = *(const half8*)(cur + (8+s)*512   + lane*8);
#pragma unroll
      for (int et = 0; et < 4; ++et){
        acc[et][0] = mfma16(A0, h0f[et][s], acc[et][0]);
        acc[et][1] = mfma16(A1, h0f[et][s], acc[et][1]);
      }
    }
    // packed bias for this mp (shared by all et)
    unsigned pb[4];
    pb[0] = pkrtz(b1[mp*32 + q*4 + 0], b1[mp*32 + q*4 + 1]);
    pb[1] = pkrtz(b1[mp*32 + q*4 + 2], b1[mp*32 + q*4 + 3]);
    pb[2] = pkrtz(b1[mp*32 + 16 + q*4 + 0], b1[mp*32 + 16 + q*4 + 1]);
    pb[3] = pkrtz(b1[mp*32 + 16 + q*4 + 2], b1[mp*32 + 16 + q*4 + 3]);
    half8 w2a = ldg8(W2p + mp*512 + lane*8);
    half8 w2b = ldg8(W2p + (8+mp)*512 + lane*8);
#pragma unroll
    for (int et = 0; et < 4; ++et){
      half8 h1f = cvtpackbr(acc[et][0], acc[et][1], pb);
      apf[et][0] = mfma16(w2a, h1f, apf[et][0]);
      apf[et][1] = mfma16(w2b, h1f, apf[et][1]);
    }
    if (mp < 7){
      _Float16* nxt = &sbuf[mp&1][0];
#pragma unroll
      for (int it = 0; it < 4; ++it)
        *(half8*)(nxt + it*2048 + tid*8) = stg[it];
    }
    __syncthreads();
  }
  // epilogue: pf = relu(pfT + b2) in packed f16 -> store
  unsigned pc[4];
  pc[0] = pkrtz(b2[q*4 + 0], b2[q*4 + 1]);
  pc[1] = pkrtz(b2[q*4 + 2], b2[q*4 + 3]);
  pc[2] = pkrtz(b2[16 + q*4 + 0], b2[16 + q*4 + 1]);
  pc[3] = pkrtz(b2[16 + q*4 + 2], b2[16 + q*4 + 3]);
#pragma unroll
  for (int et = 0; et < 4; ++et){
    half8 pf = cvtpackbr(apf[et][0], apf[et][1], pc);
    *(half8*)(pfp + (blockIdx.x*16 + wave*4 + et)*512 + lane*8) = pf;
  }
}

// ---- initial f1 (transposed), 16 dets per wave, 4 waves/WG ----
__global__ __launch_bounds__(256) void kF1(const float* detF, const _Float16* fc1p,
    const float* fb, _Float16* f1G){
  int lane = threadIdx.x & 63, wave = threadIdx.x >> 6;
  int q = lane >> 4, e = lane & 15;
  int det = (blockIdx.x * 4 + wave) * 16 + e;
  const f32x4 fz = {0.f, 0.f, 0.f, 0.f};
  half8 ff[4];
#pragma unroll
  for (int s = 0; s < 4; ++s){
    const float* p = detF + det*128 + s*32 + q*4;
    f32x4 x0 = *(const f32x4*)(p);
    f32x4 x1 = *(const f32x4*)(p + 16);
    union { unsigned w[4]; half8 h; } u;
    u.w[0] = pkrtz(x0[0], x0[1]); u.w[1] = pkrtz(x0[2], x0[3]);
    u.w[2] = pkrtz(x1[0], x1[1]); u.w[3] = pkrtz(x1[2], x1[3]);
    ff[s] = u.h;
  }
#pragma unroll
  for (int m = 0; m < 2; ++m){
    f32x4 a = fz;
#pragma unroll
    for (int s = 0; s < 4; ++s)
      a = mfma16(ldg8(fc1p + (m*4+s)*512 + lane*8), ff[s], a);
    f32x4 bv = *(const f32x4*)(fb + m*16 + q*4);
    unsigned u0 = pkrtz(fmaxf(a[0]+bv[0],0.f), fmaxf(a[1]+bv[1],0.f));
    unsigned u1 = pkrtz(fmaxf(a[2]+bv[2],0.f), fmaxf(a[3]+bv[3],0.f));
    *(unsigned*)(f1G + det*32 + q*8 + m*4)     = u0;
    *(unsigned*)(f1G + det*32 + q*8 + m*4 + 2) = u1;
  }
}

// ---- one graph block: edge MLP + segment max + post MLPs + residual + next f1 ----
// grid 512 x 256: 16 dets/WG, 4 dets/wave, weights in VGPRs.
// XCD-bijective swizzle (512 = 8x64): each XCD's 4 MB L2 <-> its 4 MB pfp slice,
// re-hit across the 8 serial launches. Phase-B out-layer split by wave.
__global__ __launch_bounds__(256) void kBlk(const _Float16* pfp, const _Float16* f1in,
    _Float16* f1out, const int* nI, const _Float16* pw1p, const _Float16* pw2p,
    const _Float16* post0p, const _Float16* post1p, const _Float16* outp, const _Float16* fc1pn,
    const float* bb1, const float* bb2, const float* pb0, const float* pb1, const float* ob,
    const float* fbn, const float* fin, float* fout, int doF1){
  __shared__ __align__(16) _Float16 poolS[1024];  // [2 halves][16 dets][32 halfs]
  int tid = threadIdx.x, lane = tid & 63, wave = tid >> 6;
  int q = lane >> 4, e = lane & 15;
  int bid = blockIdx.x;
  int base = ((bid & 7) * 64 + (bid >> 3)) * 16;
  const f32x4 fz = {0.f, 0.f, 0.f, 0.f};

  half8 aW1[4][3], aW2[4][2];
  f32x4 b1v[4];
  unsigned b2p[8];   // pw2 bias, packed to match cvtpack slot order
#pragma unroll
  for (int m = 0; m < 4; ++m){
#pragma unroll
    for (int k = 0; k < 3; ++k) aW1[m][k] = ldg8(pw1p + (m*3+k)*512 + lane*8);
#pragma unroll
    for (int k = 0; k < 2; ++k) aW2[m][k] = ldg8(pw2p + (m*2+k)*512 + lane*8);
    b1v[m] = *(const f32x4*)(bb1 + m*16 + q*4);
    b2p[m*2+0] = pkrtz(bb2[m*16 + q*4 + 0], bb2[m*16 + q*4 + 1]);
    b2p[m*2+1] = pkrtz(bb2[m*16 + q*4 + 2], bb2[m*16 + q*4 + 3]);
  }

  // ---- phase A: edge MLP + packed-f16 pooling (4 dets per wave) ----
  for (int dd = 0; dd < 4; ++dd){
    int d = wave*4 + dd;
    int det = base + d;
    half8 Bc = ldg8(f1in + det*32 + q*8);   // cIdxs == det for every edge of det
    int nn[4];
#pragma unroll
    for (int et = 0; et < 4; ++et) nn[et] = nI[det*64 + et*16 + e];
    half8 Bpf[4], Bn[4];
#pragma unroll
    for (int et = 0; et < 4; ++et){
      Bpf[et] = ldg8(pfp + (det*4+et)*512 + lane*8);
      Bn[et]  = ldg8(f1in + nn[et]*32 + q*8);
    }
    // et-invariant c-contribution, folded into pw1 bias
    f32x4 bcb[4];
#pragma unroll
    for (int m = 0; m < 4; ++m){
      f32x4 dc = mfma16(aW1[m][1], Bc, fz);
#pragma unroll
      for (int r = 0; r < 4; ++r) bcb[m][r] = dc[r] + b1v[m][r];
    }
    unsigned pm[8];
#pragma unroll
    for (int i = 0; i < 8; ++i) pm[i] = 0xFC00FC00u;   // (-inf, -inf)
#pragma unroll
    for (int et = 0; et < 4; ++et){
      f32x4 acc[4];
#pragma unroll
      for (int m = 0; m < 4; ++m){
        acc[m] = mfma16(aW1[m][0], Bpf[et], fz);
        acc[m] = mfma16(aW1[m][2], Bn[et], acc[m]);
      }
      f32x4 r0, r1, r2, r3;
#pragma unroll
      for (int r = 0; r < 4; ++r){
        r0[r] = fmaxf(acc[0][r] + bcb[0][r], 0.f);
        r1[r] = fmaxf(acc[1][r] + bcb[1][r], 0.f);
        r2[r] = fmaxf(acc[2][r] + bcb[2][r], 0.f);
        r3[r] = fmaxf(acc[3][r] + bcb[3][r], 0.f);
      }
      half8 h1a = cvtpack(r0, r1);
      half8 h1b = cvtpack(r2, r3);
      f32x4 a2[4];
#pragma unroll
      for (int m = 0; m < 4; ++m){
        a2[m] = mfma16(aW2[m][0], h1a, fz);
        a2[m] = mfma16(aW2[m][1], h1b, a2[m]);
      }
      // pack raw a2 (bias+relu deferred past the max) and pk-max accumulate
      union { half8 h; unsigned w[4]; } uA, uB;
      uA.h = cvtpack(a2[0], a2[1]);
      uB.h = cvtpack(a2[2], a2[3]);
#pragma unroll
      for (int i = 0; i < 4; ++i){
        pm[i]   = hmax2u(pm[i],   uA.w[i]);
        pm[4+i] = hmax2u(pm[4+i], uB.w[i]);
      }
    }
    // butterfly max over the 16 edge columns (packed)
#pragma unroll
    for (int s = 1; s <= 8; s <<= 1){
#pragma unroll
      for (int i = 0; i < 8; ++i)
        pm[i] = hmax2u(pm[i], __shfl_xor(pm[i], s));
    }
    // deferred bias + relu (packed)
#pragma unroll
    for (int i = 0; i < 8; ++i)
      pm[i] = hmax2u(hadd2u(pm[i], b2p[i]), 0u);
    if (e == 0){
      union { unsigned w[4]; half8 h; } o0, o1;
#pragma unroll
      for (int i = 0; i < 4; ++i){ o0.w[i] = pm[i]; o1.w[i] = pm[4+i]; }
      *(half8*)(poolS + d*32 + q*8)       = o0.h;   // k 0..31
      *(half8*)(poolS + 512 + d*32 + q*8) = o1.h;   // k 32..63
    }
  }
  __syncthreads();

  // ---- phase B: post MLPs + residual + next f1 (16 dets as frag cols) ----
  half8 Bp0 = *(const half8*)(poolS + e*32 + q*8);
  half8 Bp1 = *(const half8*)(poolS + 512 + e*32 + q*8);
  int det = base + e;
  f32x4 t0[4];
#pragma unroll
  for (int m = 0; m < 4; ++m){
    f32x4 a = mfma16(ldg8(post0p + (m*2)*512   + lane*8), Bp0, fz);
    a = mfma16(ldg8(post0p + (m*2+1)*512 + lane*8), Bp1, a);
    f32x4 bv = *(const f32x4*)(pb0 + m*16 + q*4);
#pragma unroll
    for (int r = 0; r < 4; ++r) t0[m][r] = fmaxf(a[r] + bv[r], 0.f);
  }
  half8 p1a = cvtpack(t0[0], t0[1]);
  half8 p1b = cvtpack(t0[2], t0[3]);
#pragma unroll
  for (int m = 0; m < 4; ++m){
    f32x4 a = mfma16(ldg8(post1p + (m*2)*512   + lane*8), p1a, fz);
    a = mfma16(ldg8(post1p + (m*2+1)*512 + lane*8), p1b, a);
    f32x4 bv = *(const f32x4*)(pb1 + m*16 + q*4);
#pragma unroll
    for (int r = 0; r < 4; ++r) t0[m][r] = fmaxf(a[r] + bv[r], 0.f);
  }
  half8 p2a = cvtpack(t0[0], t0[1]);
  half8 p2b = cvtpack(t0[2], t0[3]);
  if (wave == 0){
    // wave 0: all 8 out-tiles (needed for fused next-f1), stores m=0,1
    f32x4 fr[8];
#pragma unroll
    for (int m = 0; m < 8; ++m){
      f32x4 a = mfma16(ldg8(outp + (m*2)*512   + lane*8), p2a, fz);
      a = mfma16(ldg8(outp + (m*2+1)*512 + lane*8), p2b, a);
      f32x4 bv = *(const f32x4*)(ob + m*16 + q*4);
      f32x4 fv = *(const f32x4*)(fin + det*128 + m*16 + q*4);
#pragma unroll
      for (int r = 0; r < 4; ++r) fr[m][r] = fmaxf(fv[r] + a[r] + bv[r], 0.f);
    }
    *(f32x4*)(fout + det*128 + 0*16 + q*4) = fr[0];
    *(f32x4*)(fout + det*128 + 1*16 + q*4) = fr[1];
    if (doF1){
      half8 ff[4];
#pragma unroll
      for (int s = 0; s < 4; ++s) ff[s] = cvtpack(fr[2*s], fr[2*s+1]);
#pragma unroll
      for (int m = 0; m < 2; ++m){
        f32x4 a = fz;
#pragma unroll
        for (int s = 0; s < 4; ++s)
          a = mfma16(ldg8(fc1pn + (m*4+s)*512 + lane*8), ff[s], a);
        f32x4 bv = *(const f32x4*)(fbn + m*16 + q*4);
        unsigned u0 = pkrtz(fmaxf(a[0]+bv[0],0.f), fmaxf(a[1]+bv[1],0.f));
        unsigned u1 = pkrtz(fmaxf(a[2]+bv[2],0.f), fmaxf(a[3]+bv[3],0.f));
        *(unsigned*)(f1out + det*32 + q*8 + m*4)     = u0;
        *(unsigned*)(f1out + det*32 + q*8 + m*4 + 2) = u1;
      }
    }
  } else {
    // waves 1-3: only their own 2 out-tiles (saves 12 MFMA + 6 residual loads)
#pragma unroll
    for (int mm = 0; mm < 2; ++mm){
      int m = wave*2 + mm;
      f32x4 a = mfma16(ldg8(outp + (m*2)*512   + lane*8), p2a, fz);
      a = mfma16(ldg8(outp + (m*2+1)*512 + lane*8), p2b, a);
      f32x4 bv = *(const f32x4*)(ob + m*16 + q*4);
      f32x4 fv = *(const f32x4*)(fin + det*128 + m*16 + q*4);
      f32x4 fr;
#pragma unroll
      for (int r = 0; r < 4; ++r) fr[r] = fmaxf(fv[r] + a[r] + bv[r], 0.f);
      *(f32x4*)(fout + det*128 + m*16 + q*4) = fr;
    }
  }
}

extern "C" void kernel_launch(void* const* d_in, const int* in_sizes, int n_in,
                              void* d_out, int out_size, void* d_ws, size_t ws_size,
                              hipStream_t stream){
  const float* detScores   = (const float*)d_in[0];
  const float* dtBoxes     = (const float*)d_in[1];
  const float* detFeatures = (const float*)d_in[2];
  const int*   cI          = (const int*)d_in[3];
  const int*   nI          = (const int*)d_in[4];
  const float* pwW0 = (const float*)d_in[5];
  const float* pwb0 = (const float*)d_in[6];
  const float* pwW1 = (const float*)d_in[7];
  const float* pwb1 = (const float*)d_in[8];
  const float* pwW2 = (const float*)d_in[9];
  const float* pwb2 = (const float*)d_in[10];
  const float* fc1W = (const float*)d_in[11];
  const float* fc1b = (const float*)d_in[12];
  const float* pw1W = (const float*)d_in[13];
  const float* pw1b = (const float*)d_in[14];
  const float* pw2W = (const float*)d_in[15];
  const float* pw2b = (const float*)d_in[16];
  const float* postW = (const float*)d_in[17];
  const float* postb = (const float*)d_in[18];
  const float* outW  = (const float*)d_in[19];
  const float* outb  = (const float*)d_in[20];

  _Float16* wsh  = (_Float16*)d_ws;
  float*    fbuf = (float*)((char*)d_ws + OFF_FBUF_BYTES);
  _Float16* f1A  = wsh + OFF_F1A;
  _Float16* f1B  = wsh + OFF_F1B;
  _Float16* pfp  = wsh + OFF_PFP;

  kPrep<<<160, 256, 0, stream>>>(pwW0, pwb0, pwW1, pwW2, fc1W, pw1W, pw2W, postW, outW, wsh);
  kF1<<<128, 256, 0, stream>>>(detFeatures, wsh + OFF_FC1P, fc1b, f1A);
  kP<<<2048, 256, 0, stream>>>(detScores, dtBoxes, cI, nI, pwb1, pwb2,
      wsh + OFF_W0P, wsh + OFF_W1P, wsh + OFF_W2P, pfp);

  for (int i = 0; i < 8; ++i){
    int last = (i == 7);
    _Float16* fin1  = (i & 1) ? f1B : f1A;
    _Float16* fout1 = (i & 1) ? f1A : f1B;
    kBlk<<<512, 256, 0, stream>>>(pfp, fin1, fout1, nI,
        wsh + OFF_PW1P + i*6144, wsh + OFF_PW2P + i*4096,
        wsh + OFF_POSTP + i*8192, wsh + OFF_POSTP + i*8192 + 4096, wsh + OFF_OUTP + i*8192,
        wsh + OFF_FC1P + ((i+1) & 7)*4096,
        pw1b + i*64, pw2b + i*64, postb + i*128, postb + i*128 + 64, outb + i*128,
        fc1b + ((i+1) & 7)*32,
        (i == 0) ? detFeatures : fbuf, last ? (float*)d_out : fbuf, last ? 0 : 1);
  }
}

// Round 13
// 237.065 us; speedup vs baseline: 1.8532x; 1.0204x over previous
//
#include <hip/hip_runtime.h>
#include <hip/hip_bf16.h>

typedef _Float16 half8 __attribute__((ext_vector_type(8)));
typedef __fp16 fp16x2 __attribute__((ext_vector_type(2)));
typedef float f32x4 __attribute__((ext_vector_type(4)));

#define N_DETS 8192

// ---- workspace layout (offsets in _Float16 units unless noted) ----
#define OFF_W0P   0          // 16 frags x 512 (k=9 row holds pw_b0)
#define OFF_W1P   8192       // 16x8x512
#define OFF_W2P   73728      // 2x8x512
#define OFF_FC1P  81920      // 8 x (2x4x512)
#define OFF_PW1P  114688     // 8 x (4x3x512)
#define OFF_PW2P  163840     // 8 x (4x2x512)
#define OFF_POSTP 196608     // 8 x 2 x (4x2x512)
#define OFF_OUTP  262144     // 8 x (8x2x512)
#define OFF_F1A   327680     // 8192x32 f16 (pi-frag layout), ping
#define OFF_F1B   589824     // 8192x32 f16, pong
#define OFF_PFP   1114112    // 32768 edge-tiles x 512 (pi-frags of pairFeatures)
#define OFF_FBUF_BYTES 35782656  // f32 [8192][128]

// pi slot map: physical slot (g = lane>>4, j) <-> logical k = ((j>>2)<<4) + g*4 + (j&3)
// Both MFMA operands use the same map, so products pair correctly, and the D-tile
// pair (rows 0..15, 16..31) converts to a B-frag with pure in-lane packing.

__device__ inline f32x4 mfma16(half8 a, half8 b, f32x4 c){
  return __builtin_amdgcn_mfma_f32_16x16x32_f16(a, b, c, 0, 0, 0);
}
__device__ inline half8 ldg8(const _Float16* p){ return *(const half8*)p; }

__device__ inline unsigned pkrtz(float a, float b){
  union { fp16x2 h; unsigned u; } x;
  x.h = __builtin_amdgcn_cvt_pkrtz(a, b);
  return x.u;
}
// packed f16 max/add via direct ISA (avoids hip header overload clashes)
__device__ inline unsigned hmax2u(unsigned a, unsigned b){
  unsigned r;
  asm("v_pk_max_f16 %0, %1, %2" : "=v"(r) : "v"(a), "v"(b));
  return r;
}
__device__ inline unsigned hadd2u(unsigned a, unsigned b){
  unsigned r;
  asm("v_pk_add_f16 %0, %1, %2" : "=v"(r) : "v"(a), "v"(b));
  return r;
}

// D-pair -> B-frag under pi: slots 0-3 = A rows g*4+r, slots 4-7 = B rows 16+g*4+r.
__device__ inline half8 cvtpack(f32x4 A, f32x4 B){
  union { unsigned w[4]; half8 h; } r;
  r.w[0] = pkrtz(A[0], A[1]); r.w[1] = pkrtz(A[2], A[3]);
  r.w[2] = pkrtz(B[0], B[1]); r.w[3] = pkrtz(B[2], B[3]);
  return r.h;
}
// cvtpack + packed bias + relu (deferred epilogue, f16 domain)
__device__ inline half8 cvtpackbr(f32x4 A, f32x4 B, const unsigned* pb){
  union { unsigned w[4]; half8 h; } r;
  r.w[0] = pkrtz(A[0], A[1]); r.w[1] = pkrtz(A[2], A[3]);
  r.w[2] = pkrtz(B[0], B[1]); r.w[3] = pkrtz(B[2], B[3]);
#pragma unroll
  for (int i = 0; i < 4; ++i) r.w[i] = hmax2u(hadd2u(r.w[i], pb[i]), 0u);
  return r.h;
}
// cvtpack + relu only
__device__ inline half8 cvtpackr(f32x4 A, f32x4 B){
  union { unsigned w[4]; half8 h; } r;
  r.w[0] = pkrtz(A[0], A[1]); r.w[1] = pkrtz(A[2], A[3]);
  r.w[2] = pkrtz(B[0], B[1]); r.w[3] = pkrtz(B[2], B[3]);
#pragma unroll
  for (int i = 0; i < 4; ++i) r.w[i] = hmax2u(r.w[i], 0u);
  return r.h;
}

// ---- weight packing in pi order (valid as A-frags of W^T) ----
__device__ inline void packB(const float* W, int Ksrc, int Nn, _Float16* dst, int sig){
  int ns = (Ksrc + 31) >> 5;
  int t = sig / (ns * 64);
  int rem = sig - t * ns * 64;
  int s = rem >> 6;
  int l = rem & 63;
  int col = t * 16 + (l & 15);
  int g = l >> 4;
  half8 v;
#pragma unroll
  for (int j = 0; j < 8; ++j){
    int k = s*32 + ((j>>2)<<4) + g*4 + (j&3);
    v[j] = (_Float16)((k < Ksrc) ? W[k * Nn + col] : 0.f);
  }
  *(half8*)(dst + sig * 8) = v;
}

__device__ inline void packW0(const float* W, const float* bias, _Float16* dst, int sig){
  int t = sig >> 6, l = sig & 63;
  int col = t * 16 + (l & 15);
  int g = l >> 4;
  half8 v;
#pragma unroll
  for (int j = 0; j < 8; ++j){
    int k = ((j>>2)<<4) + g*4 + (j&3);
    float x = 0.f;
    if (k < 9) x = W[k * 256 + col];
    else if (k == 9) x = bias[col];
    v[j] = (_Float16)x;
  }
  *(half8*)(dst + sig * 8) = v;
}

__global__ __launch_bounds__(256) void kPrep(const float* pwW0, const float* pwb0,
    const float* pwW1, const float* pwW2,
    const float* fc1W, const float* pw1W, const float* pw2W, const float* postW, const float* outW,
    _Float16* wsh){
  int sig = blockIdx.x * 256 + threadIdx.x;
  if (sig < 1024){ packW0(pwW0, pwb0, wsh + OFF_W0P, sig); return; }
  sig -= 1024;
  if (sig < 8192){ packB(pwW1, 256, 256, wsh + OFF_W1P, sig); return; }
  sig -= 8192;
  if (sig < 1024){ packB(pwW2, 256, 32, wsh + OFF_W2P, sig); return; }
  sig -= 1024;
  int i = sig / 3840;
  int q = sig - i * 3840;
  if (q < 512){ packB(fc1W + i*4096, 128, 32, wsh + OFF_FC1P + i*4096, q); return; }
  q -= 512;
  if (q < 768){ packB(pw1W + i*6144, 96, 64, wsh + OFF_PW1P + i*6144, q); return; }
  q -= 768;
  if (q < 512){ packB(pw2W + i*4096, 64, 64, wsh + OFF_PW2P + i*4096, q); return; }
  q -= 512;
  if (q < 512){ packB(postW + i*8192, 64, 64, wsh + OFF_POSTP + i*8192, q); return; }
  q -= 512;
  if (q < 512){ packB(postW + i*8192 + 4096, 64, 64, wsh + OFF_POSTP + i*8192 + 4096, q); return; }
  q -= 512;
  packB(outW + i*8192, 64, 128, wsh + OFF_OUTP + i*8192, q);
}

// ---- fused pairwise MLP: 256 edges/WG (256 thr, 4 waves), 4 e-tiles/wave ----
__global__ __launch_bounds__(256, 2) void kP(const float* scores, const float* boxes,
    const int* cI, const int* nI, const float* b1, const float* b2,
    const _Float16* W0p, const _Float16* W1p, const _Float16* W2p, _Float16* pfp){
  __shared__ __align__(16) _Float16 sbuf[2][8192];
  __shared__ __align__(16) _Float16 rawp[8192];
  int tid = threadIdx.x;
  int lane = tid & 63, wave = tid >> 6;
  const f32x4 fz = {0.f, 0.f, 0.f, 0.f};

  // prologue: issue W0 + slice0 loads (reg-staged), zero raw buffer
  half8 w0ld[4], s0ld[4];
#pragma unroll
  for (int it = 0; it < 4; ++it){
    w0ld[it] = ldg8(W0p + it*2048 + tid*8);
    s0ld[it] = ldg8(W1p + it*2048 + tid*8);
  }
  {
    half8 z = {0,0,0,0,0,0,0,0};
#pragma unroll
    for (int it = 0; it < 4; ++it) *(half8*)(rawp + it*2048 + tid*8) = z;
  }
  __syncthreads();
  {
    int e = blockIdx.x*256 + tid;
    int c = cI[e], n = nI[e];
    float cx1 = boxes[c*4+0], cy1 = boxes[c*4+1], cx2 = boxes[c*4+2], cy2 = boxes[c*4+3];
    float nx1 = boxes[n*4+0], ny1 = boxes[n*4+1], nx2 = boxes[n*4+2], ny2 = boxes[n*4+3];
    float cw = cx2-cx1, ch = cy2-cy1, nw = nx2-nx1, nh = ny2-ny1;
    float ca = cw*ch, na = nw*nh;
    float ix = fmaxf(fminf(cx2,nx2) - fmaxf(cx1,nx1), 0.f);
    float iy = fmaxf(fminf(cy2,ny2) - fmaxf(cy1,ny1), 0.f);
    float inter = ix*iy;
    float iou = inter / (ca + na - inter);
    float cs = (cw + ch) * 0.5f;
    float xd = (nx1 + nw*0.5f) - (cx1 + cw*0.5f);
    float yd = (ny1 + nh*0.5f) - (cy1 + ch*0.5f);
    float l2 = sqrtf(xd*xd + yd*yd) / cs;
    float wd = log2f(nw/cw), hd = log2f(nh/ch);
    float ad = log2f(nw/nh) - log2f(cw/ch);
    float rv[10] = {scores[c], scores[n], iou, xd/cs, yd/cs, l2, wd, hd, ad, 1.0f};
    int base = (tid >> 4) * 512;   // e-tile region (16 tiles/WG)
    int r = tid & 15;
#pragma unroll
    for (int k = 0; k < 10; ++k)
      rawp[base + (((k>>2)&3)*16 + r)*8 + (k&3)] = (_Float16)rv[k];   // pi position
  }
#pragma unroll
  for (int it = 0; it < 4; ++it){
    *(half8*)(&sbuf[0][0] + it*2048 + tid*8) = w0ld[it];
    *(half8*)(&sbuf[1][0] + it*2048 + tid*8) = s0ld[it];
  }
  __syncthreads();

  // L0: h0T = W0T * rawT  (bias folded via raw[9]=1; relu in packed f16)
  half8 h0f[4][8];
  {
    half8 braw[4];
#pragma unroll
    for (int et = 0; et < 4; ++et)
      braw[et] = *(const half8*)(rawp + ((wave*4+et)*64 + lane)*8);
#pragma unroll
    for (int mp = 0; mp < 8; ++mp){
      half8 A0 = *(const half8*)(&sbuf[0][0] + (2*mp)*512   + lane*8);
      half8 A1 = *(const half8*)(&sbuf[0][0] + (2*mp+1)*512 + lane*8);
#pragma unroll
      for (int et = 0; et < 4; ++et){
        f32x4 a = mfma16(A0, braw[et], fz);
        f32x4 b = mfma16(A1, braw[et], fz);
        h0f[et][mp] = cvtpackr(a, b);
      }
    }
  }
  __syncthreads();   // protect sbuf[0] before slice1 is written into it

  // L1 + fused L2: loop over 8 output m-pairs of h1, double-buffered slices
  int q = lane >> 4;
  f32x4 apf[4][2];
#pragma unroll
  for (int et = 0; et < 4; ++et){ apf[et][0] = fz; apf[et][1] = fz; }
  for (int mp = 0; mp < 8; ++mp){
    const _Float16* cur = &sbuf[(mp+1)&1][0];
    half8 stg[4];
    if (mp < 7){
#pragma unroll
      for (int it = 0; it < 4; ++it)
        stg[it] = ldg8(W1p + (mp+1)*8192 + it*2048 + tid*8);
    }
    f32x4 acc[4][2];
#pragma unroll
    for (int et = 0; et < 4; ++et){ acc[et][0] = fz; acc[et][1] = fz; }
#pragma unroll
    for (int s = 0; s < 8; ++s){
      half8 A0 = *(const half8*)(cur + s*512       + lane*8);
      half8 A1 = *(const half8*)(cur + (8+s)*512   + lane*8);
#pragma unroll
      for (int et = 0; et < 4; ++et){
        acc[et][0] = mfma16(A0, h0f[et][s], acc[et][0]);
        acc[et][1] = mfma16(A1, h0f[et][s], acc[et][1]);
      }
    }
    // packed bias for this mp (shared by all et)
    unsigned pb[4];
    pb[0] = pkrtz(b1[mp*32 + q*4 + 0], b1[mp*32 + q*4 + 1]);
    pb[1] = pkrtz(b1[mp*32 + q*4 + 2], b1[mp*32 + q*4 + 3]);
    pb[2] = pkrtz(b1[mp*32 + 16 + q*4 + 0], b1[mp*32 + 16 + q*4 + 1]);
    pb[3] = pkrtz(b1[mp*32 + 16 + q*4 + 2], b1[mp*32 + 16 + q*4 + 3]);
    half8 w2a = ldg8(W2p + mp*512 + lane*8);
    half8 w2b = ldg8(W2p + (8+mp)*512 + lane*8);
#pragma unroll
    for (int et = 0; et < 4; ++et){
      half8 h1f = cvtpackbr(acc[et][0], acc[et][1], pb);
      apf[et][0] = mfma16(w2a, h1f, apf[et][0]);
      apf[et][1] = mfma16(w2b, h1f, apf[et][1]);
    }
    if (mp < 7){
      _Float16* nxt = &sbuf[mp&1][0];
#pragma unroll
      for (int it = 0; it < 4; ++it)
        *(half8*)(nxt + it*2048 + tid*8) = stg[it];
    }
    __syncthreads();
  }
  // epilogue: pf = relu(pfT + b2) in packed f16 -> store
  unsigned pc[4];
  pc[0] = pkrtz(b2[q*4 + 0], b2[q*4 + 1]);
  pc[1] = pkrtz(b2[q*4 + 2], b2[q*4 + 3]);
  pc[2] = pkrtz(b2[16 + q*4 + 0], b2[16 + q*4 + 1]);
  pc[3] = pkrtz(b2[16 + q*4 + 2], b2[16 + q*4 + 3]);
#pragma unroll
  for (int et = 0; et < 4; ++et){
    half8 pf = cvtpackbr(apf[et][0], apf[et][1], pc);
    *(half8*)(pfp + (blockIdx.x*16 + wave*4 + et)*512 + lane*8) = pf;
  }
}

// ---- initial f1 (transposed), 16 dets per wave, 4 waves/WG ----
__global__ __launch_bounds__(256) void kF1(const float* detF, const _Float16* fc1p,
    const float* fb, _Float16* f1G){
  int lane = threadIdx.x & 63, wave = threadIdx.x >> 6;
  int q = lane >> 4, e = lane & 15;
  int det = (blockIdx.x * 4 + wave) * 16 + e;
  const f32x4 fz = {0.f, 0.f, 0.f, 0.f};
  half8 ff[4];
#pragma unroll
  for (int s = 0; s < 4; ++s){
    const float* p = detF + det*128 + s*32 + q*4;
    f32x4 x0 = *(const f32x4*)(p);
    f32x4 x1 = *(const f32x4*)(p + 16);
    union { unsigned w[4]; half8 h; } u;
    u.w[0] = pkrtz(x0[0], x0[1]); u.w[1] = pkrtz(x0[2], x0[3]);
    u.w[2] = pkrtz(x1[0], x1[1]); u.w[3] = pkrtz(x1[2], x1[3]);
    ff[s] = u.h;
  }
#pragma unroll
  for (int m = 0; m < 2; ++m){
    f32x4 a = fz;
#pragma unroll
    for (int s = 0; s < 4; ++s)
      a = mfma16(ldg8(fc1p + (m*4+s)*512 + lane*8), ff[s], a);
    f32x4 bv = *(const f32x4*)(fb + m*16 + q*4);
    unsigned u0 = pkrtz(fmaxf(a[0]+bv[0],0.f), fmaxf(a[1]+bv[1],0.f));
    unsigned u1 = pkrtz(fmaxf(a[2]+bv[2],0.f), fmaxf(a[3]+bv[3],0.f));
    *(unsigned*)(f1G + det*32 + q*8 + m*4)     = u0;
    *(unsigned*)(f1G + det*32 + q*8 + m*4 + 2) = u1;
  }
}

// ---- one graph block: edge MLP + segment max + post MLPs + residual + next f1 ----
// grid 512 x 256: 16 dets/WG, 4 dets/wave, weights in VGPRs.
// XCD-bijective swizzle; depth-1 pipeline on the det loop (nI/Bc prefetch);
// phase B is race-free: each wave owns its 2 out-rows; next-f1 fragments are
// staged through LDS behind a barrier (values are wave-invariant per lane).
__global__ __launch_bounds__(256) void kBlk(const _Float16* pfp, const _Float16* f1in,
    _Float16* f1out, const int* nI, const _Float16* pw1p, const _Float16* pw2p,
    const _Float16* post0p, const _Float16* post1p, const _Float16* outp, const _Float16* fc1pn,
    const float* bb1, const float* bb2, const float* pb0, const float* pb1, const float* ob,
    const float* fbn, const float* fin, float* fout, int doF1){
  __shared__ __align__(16) _Float16 poolS[1024];  // [2 halves][16 dets][32 halfs]
  __shared__ __align__(16) _Float16 ffS[2048];    // next-f1 B-frag staging (4 waves x 64 x 8)
  int tid = threadIdx.x, lane = tid & 63, wave = tid >> 6;
  int q = lane >> 4, e = lane & 15;
  int bid = blockIdx.x;
  int base = ((bid & 7) * 64 + (bid >> 3)) * 16;   // XCD-bijective det range
  const f32x4 fz = {0.f, 0.f, 0.f, 0.f};

  half8 aW1[4][3], aW2[4][2];
  f32x4 b1v[4];
  unsigned b2p[8];   // pw2 bias, packed to match cvtpack slot order
#pragma unroll
  for (int m = 0; m < 4; ++m){
#pragma unroll
    for (int k = 0; k < 3; ++k) aW1[m][k] = ldg8(pw1p + (m*3+k)*512 + lane*8);
#pragma unroll
    for (int k = 0; k < 2; ++k) aW2[m][k] = ldg8(pw2p + (m*2+k)*512 + lane*8);
    b1v[m] = *(const f32x4*)(bb1 + m*16 + q*4);
    b2p[m*2+0] = pkrtz(bb2[m*16 + q*4 + 0], bb2[m*16 + q*4 + 1]);
    b2p[m*2+1] = pkrtz(bb2[m*16 + q*4 + 2], bb2[m*16 + q*4 + 3]);
  }

  // ---- phase A: edge MLP + packed-f16 pooling (4 dets/wave, depth-1 pipeline) ----
  int nnC[4]; half8 BcC;
  {
    int det0 = base + wave*4;
#pragma unroll
    for (int et = 0; et < 4; ++et) nnC[et] = nI[det0*64 + et*16 + e];
    BcC = ldg8(f1in + det0*32 + q*8);
  }
#pragma unroll 1
  for (int dd = 0; dd < 4; ++dd){
    int d = wave*4 + dd;
    int det = base + d;
    // current det's gathers (addresses ready: nnC prefetched last iteration)
    half8 Bpf[4], Bn[4];
#pragma unroll
    for (int et = 0; et < 4; ++et){
      Bpf[et] = ldg8(pfp + (det*4+et)*512 + lane*8);
      Bn[et]  = ldg8(f1in + nnC[et]*32 + q*8);
    }
    // prefetch next det's indices + c-row (latency hidden under this det's compute)
    int nnN[4]; half8 BcN;
    if (dd < 3){
      int detn = det + 1;
#pragma unroll
      for (int et = 0; et < 4; ++et) nnN[et] = nI[detn*64 + et*16 + e];
      BcN = ldg8(f1in + detn*32 + q*8);
    }
    // et-invariant c-contribution, folded into pw1 bias
    f32x4 bcb[4];
#pragma unroll
    for (int m = 0; m < 4; ++m){
      f32x4 dc = mfma16(aW1[m][1], BcC, fz);
#pragma unroll
      for (int r = 0; r < 4; ++r) bcb[m][r] = dc[r] + b1v[m][r];
    }
    unsigned pm[8];
#pragma unroll
    for (int i = 0; i < 8; ++i) pm[i] = 0xFC00FC00u;   // (-inf, -inf)
#pragma unroll
    for (int et = 0; et < 4; ++et){
      f32x4 acc[4];
#pragma unroll
      for (int m = 0; m < 4; ++m){
        acc[m] = mfma16(aW1[m][0], Bpf[et], fz);
        acc[m] = mfma16(aW1[m][2], Bn[et], acc[m]);
      }
      f32x4 r0, r1, r2, r3;
#pragma unroll
      for (int r = 0; r < 4; ++r){
        r0[r] = fmaxf(acc[0][r] + bcb[0][r], 0.f);
        r1[r] = fmaxf(acc[1][r] + bcb[1][r], 0.f);
        r2[r] = fmaxf(acc[2][r] + bcb[2][r], 0.f);
        r3[r] = fmaxf(acc[3][r] + bcb[3][r], 0.f);
      }
      half8 h1a = cvtpack(r0, r1);
      half8 h1b = cvtpack(r2, r3);
      f32x4 a2[4];
#pragma unroll
      for (int m = 0; m < 4; ++m){
        a2[m] = mfma16(aW2[m][0], h1a, fz);
        a2[m] = mfma16(aW2[m][1], h1b, a2[m]);
      }
      // pack raw a2 (bias+relu deferred past the max) and pk-max accumulate
      union { half8 h; unsigned w[4]; } uA, uB;
      uA.h = cvtpack(a2[0], a2[1]);
      uB.h = cvtpack(a2[2], a2[3]);
#pragma unroll
      for (int i = 0; i < 4; ++i){
        pm[i]   = hmax2u(pm[i],   uA.w[i]);
        pm[4+i] = hmax2u(pm[4+i], uB.w[i]);
      }
    }
    // butterfly max over the 16 edge columns (packed)
#pragma unroll
    for (int s = 1; s <= 8; s <<= 1){
#pragma unroll
      for (int i = 0; i < 8; ++i)
        pm[i] = hmax2u(pm[i], __shfl_xor(pm[i], s));
    }
    // deferred bias + relu (packed)
#pragma unroll
    for (int i = 0; i < 8; ++i)
      pm[i] = hmax2u(hadd2u(pm[i], b2p[i]), 0u);
    if (e == 0){
      union { unsigned w[4]; half8 h; } o0, o1;
#pragma unroll
      for (int i = 0; i < 4; ++i){ o0.w[i] = pm[i]; o1.w[i] = pm[4+i]; }
      *(half8*)(poolS + d*32 + q*8)       = o0.h;   // k 0..31
      *(half8*)(poolS + 512 + d*32 + q*8) = o1.h;   // k 32..63
    }
    // rotate the pipeline registers
    if (dd < 3){
#pragma unroll
      for (int et = 0; et < 4; ++et) nnC[et] = nnN[et];
      BcC = BcN;
    }
  }
  __syncthreads();

  // ---- phase B: post MLPs + residual + next f1 (16 dets as frag cols) ----
  half8 Bp0 = *(const half8*)(poolS + e*32 + q*8);
  half8 Bp1 = *(const half8*)(poolS + 512 + e*32 + q*8);
  int det = base + e;
  f32x4 t0[4];
#pragma unroll
  for (int m = 0; m < 4; ++m){
    f32x4 a = mfma16(ldg8(post0p + (m*2)*512   + lane*8), Bp0, fz);
    a = mfma16(ldg8(post0p + (m*2+1)*512 + lane*8), Bp1, a);
    f32x4 bv = *(const f32x4*)(pb0 + m*16 + q*4);
#pragma unroll
    for (int r = 0; r < 4; ++r) t0[m][r] = fmaxf(a[r] + bv[r], 0.f);
  }
  half8 p1a = cvtpack(t0[0], t0[1]);
  half8 p1b = cvtpack(t0[2], t0[3]);
#pragma unroll
  for (int m = 0; m < 4; ++m){
    f32x4 a = mfma16(ldg8(post1p + (m*2)*512   + lane*8), p1a, fz);
    a = mfma16(ldg8(post1p + (m*2+1)*512 + lane*8), p1b, a);
    f32x4 bv = *(const f32x4*)(pb1 + m*16 + q*4);
#pragma unroll
    for (int r = 0; r < 4; ++r) t0[m][r] = fmaxf(a[r] + bv[r], 0.f);
  }
  half8 p2a = cvtpack(t0[0], t0[1]);
  half8 p2b = cvtpack(t0[2], t0[3]);
  // each wave owns out-rows m0 = 2*wave, m0+1 — no cross-wave read/write overlap
  int m0 = wave*2, m1 = m0 + 1;
  f32x4 fr0, fr1;
  {
    f32x4 a = mfma16(ldg8(outp + (m0*2)*512   + lane*8), p2a, fz);
    a = mfma16(ldg8(outp + (m0*2+1)*512 + lane*8), p2b, a);
    f32x4 bv = *(const f32x4*)(ob + m0*16 + q*4);
    f32x4 fv = *(const f32x4*)(fin + det*128 + m0*16 + q*4);
#pragma unroll
    for (int r = 0; r < 4; ++r) fr0[r] = fmaxf(fv[r] + a[r] + bv[r], 0.f);
  }
  {
    f32x4 a = mfma16(ldg8(outp + (m1*2)*512   + lane*8), p2a, fz);
    a = mfma16(ldg8(outp + (m1*2+1)*512 + lane*8), p2b, a);
    f32x4 bv = *(const f32x4*)(ob + m1*16 + q*4);
    f32x4 fv = *(const f32x4*)(fin + det*128 + m1*16 + q*4);
#pragma unroll
    for (int r = 0; r < 4; ++r) fr1[r] = fmaxf(fv[r] + a[r] + bv[r], 0.f);
  }
  *(f32x4*)(fout + det*128 + m0*16 + q*4) = fr0;
  *(f32x4*)(fout + det*128 + m1*16 + q*4) = fr1;
  if (doF1){
    // stage this wave's next-f1 B-frag (s = wave); per-lane values are
    // wave-invariant (D-layout depends only on (q,e)), so s=w matches s=0..3
    half8 ffw = cvtpack(fr0, fr1);
    *(half8*)(ffS + wave*512 + lane*8) = ffw;
    __syncthreads();
    if (wave == 0){
#pragma unroll
      for (int m = 0; m < 2; ++m){
        f32x4 a = fz;
#pragma unroll
        for (int s = 0; s < 4; ++s){
          half8 fs = *(const half8*)(ffS + s*512 + lane*8);
          a = mfma16(ldg8(fc1pn + (m*4+s)*512 + lane*8), fs, a);
        }
        f32x4 bv = *(const f32x4*)(fbn + m*16 + q*4);
        unsigned u0 = pkrtz(fmaxf(a[0]+bv[0],0.f), fmaxf(a[1]+bv[1],0.f));
        unsigned u1 = pkrtz(fmaxf(a[2]+bv[2],0.f), fmaxf(a[3]+bv[3],0.f));
        *(unsigned*)(f1out + det*32 + q*8 + m*4)     = u0;
        *(unsigned*)(f1out + det*32 + q*8 + m*4 + 2) = u1;
      }
    }
  }
}

extern "C" void kernel_launch(void* const* d_in, const int* in_sizes, int n_in,
                              void* d_out, int out_size, void* d_ws, size_t ws_size,
                              hipStream_t stream){
  const float* detScores   = (const float*)d_in[0];
  const float* dtBoxes     = (const float*)d_in[1];
  const float* detFeatures = (const float*)d_in[2];
  const int*   cI          = (const int*)d_in[3];
  const int*   nI          = (const int*)d_in[4];
  const float* pwW0 = (const float*)d_in[5];
  const float* pwb0 = (const float*)d_in[6];
  const float* pwW1 = (const float*)d_in[7];
  const float* pwb1 = (const float*)d_in[8];
  const float* pwW2 = (const float*)d_in[9];
  const float* pwb2 = (const float*)d_in[10];
  const float* fc1W = (const float*)d_in[11];
  const float* fc1b = (const float*)d_in[12];
  const float* pw1W = (const float*)d_in[13];
  const float* pw1b = (const float*)d_in[14];
  const float* pw2W = (const float*)d_in[15];
  const float* pw2b = (const float*)d_in[16];
  const float* postW = (const float*)d_in[17];
  const float* postb = (const float*)d_in[18];
  const float* outW  = (const float*)d_in[19];
  const float* outb  = (const float*)d_in[20];

  _Float16* wsh  = (_Float16*)d_ws;
  float*    fbuf = (float*)((char*)d_ws + OFF_FBUF_BYTES);
  _Float16* f1A  = wsh + OFF_F1A;
  _Float16* f1B  = wsh + OFF_F1B;
  _Float16* pfp  = wsh + OFF_PFP;

  kPrep<<<160, 256, 0, stream>>>(pwW0, pwb0, pwW1, pwW2, fc1W, pw1W, pw2W, postW, outW, wsh);
  kF1<<<128, 256, 0, stream>>>(detFeatures, wsh + OFF_FC1P, fc1b, f1A);
  kP<<<2048, 256, 0, stream>>>(detScores, dtBoxes, cI, nI, pwb1, pwb2,
      wsh + OFF_W0P, wsh + OFF_W1P, wsh + OFF_W2P, pfp);

  for (int i = 0; i < 8; ++i){
    int last = (i == 7);
    _Float16* fin1  = (i & 1) ? f1B : f1A;
    _Float16* fout1 = (i & 1) ? f1A : f1B;
    kBlk<<<512, 256, 0, stream>>>(pfp, fin1, fout1, nI,
        wsh + OFF_PW1P + i*6144, wsh + OFF_PW2P + i*4096,
        wsh + OFF_POSTP + i*8192, wsh + OFF_POSTP + i*8192 + 4096, wsh + OFF_OUTP + i*8192,
        wsh + OFF_FC1P + ((i+1) & 7)*4096,
        pw1b + i*64, pw2b + i*64, postb + i*128, postb + i*128 + 64, outb + i*128,
        fc1b + ((i+1) & 7)*32,
        (i == 0) ? detFeatures : fbuf, last ? (float*)d_out : fbuf, last ? 0 : 1);
  }
}

// Round 14
// 235.942 us; speedup vs baseline: 1.8620x; 1.0048x over previous
//
#include <hip/hip_runtime.h>
#include <hip/hip_bf16.h>

typedef _Float16 half8 __attribute__((ext_vector_type(8)));
typedef __fp16 fp16x2 __attribute__((ext_vector_type(2)));
typedef float f32x4 __attribute__((ext_vector_type(4)));

#define N_DETS 8192

// ---- workspace layout (offsets in _Float16 units unless noted) ----
#define OFF_W0P   0          // 16 frags x 512 (k=9 row holds pw_b0)
#define OFF_W1P   8192       // 16x8x512
#define OFF_W2P   73728      // 2x8x512
#define OFF_FC1P  81920      // 8 x (2x4x512)
#define OFF_PW1P  114688     // 8 x (4x3x512)
#define OFF_PW2P  163840     // 8 x (4x2x512)
#define OFF_POSTP 196608     // 8 x 2 x (4x2x512)
#define OFF_OUTP  262144     // 8 x (8x2x512)
#define OFF_F1A   327680     // 8192x32 f16 (pi-frag layout), ping
#define OFF_F1B   589824     // 8192x32 f16, pong
#define OFF_PFP   1114112    // 32768 edge-tiles x 512 (pi-frags of pairFeatures)
#define OFF_FBUF_BYTES 35782656  // f32 [8192][128]

// pi slot map: physical slot (g = lane>>4, j) <-> logical k = ((j>>2)<<4) + g*4 + (j&3)
// Both MFMA operands use the same map, so products pair correctly, and the D-tile
// pair (rows 0..15, 16..31) converts to a B-frag with pure in-lane packing.

__device__ inline f32x4 mfma16(half8 a, half8 b, f32x4 c){
  return __builtin_amdgcn_mfma_f32_16x16x32_f16(a, b, c, 0, 0, 0);
}
__device__ inline half8 ldg8(const _Float16* p){ return *(const half8*)p; }

__device__ inline unsigned pkrtz(float a, float b){
  union { fp16x2 h; unsigned u; } x;
  x.h = __builtin_amdgcn_cvt_pkrtz(a, b);
  return x.u;
}
// packed f16 max/add via direct ISA (avoids hip header overload clashes)
__device__ inline unsigned hmax2u(unsigned a, unsigned b){
  unsigned r;
  asm("v_pk_max_f16 %0, %1, %2" : "=v"(r) : "v"(a), "v"(b));
  return r;
}
__device__ inline unsigned hadd2u(unsigned a, unsigned b){
  unsigned r;
  asm("v_pk_add_f16 %0, %1, %2" : "=v"(r) : "v"(a), "v"(b));
  return r;
}

// D-pair -> B-frag under pi: slots 0-3 = A rows g*4+r, slots 4-7 = B rows 16+g*4+r.
__device__ inline half8 cvtpack(f32x4 A, f32x4 B){
  union { unsigned w[4]; half8 h; } r;
  r.w[0] = pkrtz(A[0], A[1]); r.w[1] = pkrtz(A[2], A[3]);
  r.w[2] = pkrtz(B[0], B[1]); r.w[3] = pkrtz(B[2], B[3]);
  return r.h;
}
// cvtpack + packed bias + relu (deferred epilogue, f16 domain)
__device__ inline half8 cvtpackbr(f32x4 A, f32x4 B, const unsigned* pb){
  union { unsigned w[4]; half8 h; } r;
  r.w[0] = pkrtz(A[0], A[1]); r.w[1] = pkrtz(A[2], A[3]);
  r.w[2] = pkrtz(B[0], B[1]); r.w[3] = pkrtz(B[2], B[3]);
#pragma unroll
  for (int i = 0; i < 4; ++i) r.w[i] = hmax2u(hadd2u(r.w[i], pb[i]), 0u);
  return r.h;
}
// cvtpack + relu only
__device__ inline half8 cvtpackr(f32x4 A, f32x4 B){
  union { unsigned w[4]; half8 h; } r;
  r.w[0] = pkrtz(A[0], A[1]); r.w[1] = pkrtz(A[2], A[3]);
  r.w[2] = pkrtz(B[0], B[1]); r.w[3] = pkrtz(B[2], B[3]);
#pragma unroll
  for (int i = 0; i < 4; ++i) r.w[i] = hmax2u(r.w[i], 0u);
  return r.h;
}

// ---- weight packing in pi order (valid as A-frags of W^T) ----
__device__ inline void packB(const float* W, int Ksrc, int Nn, _Float16* dst, int sig){
  int ns = (Ksrc + 31) >> 5;
  int t = sig / (ns * 64);
  int rem = sig - t * ns * 64;
  int s = rem >> 6;
  int l = rem & 63;
  int col = t * 16 + (l & 15);
  int g = l >> 4;
  half8 v;
#pragma unroll
  for (int j = 0; j < 8; ++j){
    int k = s*32 + ((j>>2)<<4) + g*4 + (j&3);
    v[j] = (_Float16)((k < Ksrc) ? W[k * Nn + col] : 0.f);
  }
  *(half8*)(dst + sig * 8) = v;
}

__device__ inline void packW0(const float* W, const float* bias, _Float16* dst, int sig){
  int t = sig >> 6, l = sig & 63;
  int col = t * 16 + (l & 15);
  int g = l >> 4;
  half8 v;
#pragma unroll
  for (int j = 0; j < 8; ++j){
    int k = ((j>>2)<<4) + g*4 + (j&3);
    float x = 0.f;
    if (k < 9) x = W[k * 256 + col];
    else if (k == 9) x = bias[col];
    v[j] = (_Float16)x;
  }
  *(half8*)(dst + sig * 8) = v;
}

__global__ __launch_bounds__(256) void kPrep(const float* pwW0, const float* pwb0,
    const float* pwW1, const float* pwW2,
    const float* fc1W, const float* pw1W, const float* pw2W, const float* postW, const float* outW,
    _Float16* wsh){
  int sig = blockIdx.x * 256 + threadIdx.x;
  if (sig < 1024){ packW0(pwW0, pwb0, wsh + OFF_W0P, sig); return; }
  sig -= 1024;
  if (sig < 8192){ packB(pwW1, 256, 256, wsh + OFF_W1P, sig); return; }
  sig -= 8192;
  if (sig < 1024){ packB(pwW2, 256, 32, wsh + OFF_W2P, sig); return; }
  sig -= 1024;
  int i = sig / 3840;
  int q = sig - i * 3840;
  if (q < 512){ packB(fc1W + i*4096, 128, 32, wsh + OFF_FC1P + i*4096, q); return; }
  q -= 512;
  if (q < 768){ packB(pw1W + i*6144, 96, 64, wsh + OFF_PW1P + i*6144, q); return; }
  q -= 768;
  if (q < 512){ packB(pw2W + i*4096, 64, 64, wsh + OFF_PW2P + i*4096, q); return; }
  q -= 512;
  if (q < 512){ packB(postW + i*8192, 64, 64, wsh + OFF_POSTP + i*8192, q); return; }
  q -= 512;
  if (q < 512){ packB(postW + i*8192 + 4096, 64, 64, wsh + OFF_POSTP + i*8192 + 4096, q); return; }
  q -= 512;
  packB(outW + i*8192, 64, 128, wsh + OFF_OUTP + i*8192, q);
}

// ---- fused pairwise MLP: 256 edges/WG (256 thr, 4 waves), 4 e-tiles/wave ----
// LDS 32 KB: the raw-feature frags time-share sbuf[1] with the W1 slice-0
// staging (raw is dead after L0; slice 0 is first read at mp=0).
__global__ __launch_bounds__(256, 2) void kP(const float* scores, const float* boxes,
    const int* cI, const int* nI, const float* b1, const float* b2,
    const _Float16* W0p, const _Float16* W1p, const _Float16* W2p, _Float16* pfp){
  __shared__ __align__(16) _Float16 sbuf[2][8192];
  int tid = threadIdx.x;
  int lane = tid & 63, wave = tid >> 6;
  const f32x4 fz = {0.f, 0.f, 0.f, 0.f};

  // prologue: issue W0 + slice0 loads (reg-staged), zero the raw region (sbuf[1])
  half8 w0ld[4], s0ld[4];
#pragma unroll
  for (int it = 0; it < 4; ++it){
    w0ld[it] = ldg8(W0p + it*2048 + tid*8);
    s0ld[it] = ldg8(W1p + it*2048 + tid*8);
  }
  {
    half8 z = {0,0,0,0,0,0,0,0};
#pragma unroll
    for (int it = 0; it < 4; ++it) *(half8*)(&sbuf[1][0] + it*2048 + tid*8) = z;
  }
#pragma unroll
  for (int it = 0; it < 4; ++it)
    *(half8*)(&sbuf[0][0] + it*2048 + tid*8) = w0ld[it];
  __syncthreads();
  {
    int e = blockIdx.x*256 + tid;
    int c = cI[e], n = nI[e];
    float cx1 = boxes[c*4+0], cy1 = boxes[c*4+1], cx2 = boxes[c*4+2], cy2 = boxes[c*4+3];
    float nx1 = boxes[n*4+0], ny1 = boxes[n*4+1], nx2 = boxes[n*4+2], ny2 = boxes[n*4+3];
    float cw = cx2-cx1, ch = cy2-cy1, nw = nx2-nx1, nh = ny2-ny1;
    float ca = cw*ch, na = nw*nh;
    float ix = fmaxf(fminf(cx2,nx2) - fmaxf(cx1,nx1), 0.f);
    float iy = fmaxf(fminf(cy2,ny2) - fmaxf(cy1,ny1), 0.f);
    float inter = ix*iy;
    float iou = inter / (ca + na - inter);
    float cs = (cw + ch) * 0.5f;
    float xd = (nx1 + nw*0.5f) - (cx1 + cw*0.5f);
    float yd = (ny1 + nh*0.5f) - (cy1 + ch*0.5f);
    float l2 = sqrtf(xd*xd + yd*yd) / cs;
    float wd = log2f(nw/cw), hd = log2f(nh/ch);
    float ad = log2f(nw/nh) - log2f(cw/ch);
    float rv[10] = {scores[c], scores[n], iou, xd/cs, yd/cs, l2, wd, hd, ad, 1.0f};
    int base = (tid >> 4) * 512;   // e-tile region (16 tiles/WG)
    int r = tid & 15;
#pragma unroll
    for (int k = 0; k < 10; ++k)
      sbuf[1][base + (((k>>2)&3)*16 + r)*8 + (k&3)] = (_Float16)rv[k];   // pi position
  }
  __syncthreads();

  // L0: h0T = W0T * rawT  (bias folded via raw[9]=1; relu in packed f16)
  half8 h0f[4][8];
  {
    half8 braw[4];
#pragma unroll
    for (int et = 0; et < 4; ++et)
      braw[et] = *(const half8*)(&sbuf[1][0] + ((wave*4+et)*64 + lane)*8);
#pragma unroll
    for (int mp = 0; mp < 8; ++mp){
      half8 A0 = *(const half8*)(&sbuf[0][0] + (2*mp)*512   + lane*8);
      half8 A1 = *(const half8*)(&sbuf[0][0] + (2*mp+1)*512 + lane*8);
#pragma unroll
      for (int et = 0; et < 4; ++et){
        f32x4 a = mfma16(A0, braw[et], fz);
        f32x4 b = mfma16(A1, braw[et], fz);
        h0f[et][mp] = cvtpackr(a, b);
      }
    }
  }
  __syncthreads();   // raw region dead; overwrite with W1 slice 0
#pragma unroll
  for (int it = 0; it < 4; ++it)
    *(half8*)(&sbuf[1][0] + it*2048 + tid*8) = s0ld[it];
  __syncthreads();

  // L1 + fused L2: loop over 8 output m-pairs of h1, double-buffered slices
  int q = lane >> 4;
  f32x4 apf[4][2];
#pragma unroll
  for (int et = 0; et < 4; ++et){ apf[et][0] = fz; apf[et][1] = fz; }
  for (int mp = 0; mp < 8; ++mp){
    const _Float16* cur = &sbuf[(mp+1)&1][0];
    half8 stg[4];
    if (mp < 7){
#pragma unroll
      for (int it = 0; it < 4; ++it)
        stg[it] = ldg8(W1p + (mp+1)*8192 + it*2048 + tid*8);
    }
    f32x4 acc[4][2];
#pragma unroll
    for (int et = 0; et < 4; ++et){ acc[et][0] = fz; acc[et][1] = fz; }
#pragma unroll
    for (int s = 0; s < 8; ++s){
      half8 A0 = *(const half8*)(cur + s*512       + lane*8);
      half8 A1 = *(const half8*)(cur + (8+s)*512   + lane*8);
#pragma unroll
      for (int et = 0; et < 4; ++et){
        acc[et][0] = mfma16(A0, h0f[et][s], acc[et][0]);
        acc[et][1] = mfma16(A1, h0f[et][s], acc[et][1]);
      }
    }
    // packed bias for this mp (shared by all et)
    unsigned pb[4];
    pb[0] = pkrtz(b1[mp*32 + q*4 + 0], b1[mp*32 + q*4 + 1]);
    pb[1] = pkrtz(b1[mp*32 + q*4 + 2], b1[mp*32 + q*4 + 3]);
    pb[2] = pkrtz(b1[mp*32 + 16 + q*4 + 0], b1[mp*32 + 16 + q*4 + 1]);
    pb[3] = pkrtz(b1[mp*32 + 16 + q*4 + 2], b1[mp*32 + 16 + q*4 + 3]);
    half8 w2a = ldg8(W2p + mp*512 + lane*8);
    half8 w2b = ldg8(W2p + (8+mp)*512 + lane*8);
#pragma unroll
    for (int et = 0; et < 4; ++et){
      half8 h1f = cvtpackbr(acc[et][0], acc[et][1], pb);
      apf[et][0] = mfma16(w2a, h1f, apf[et][0]);
      apf[et][1] = mfma16(w2b, h1f, apf[et][1]);
    }
    if (mp < 7){
      _Float16* nxt = &sbuf[mp&1][0];
#pragma unroll
      for (int it = 0; it < 4; ++it)
        *(half8*)(nxt + it*2048 + tid*8) = stg[it];
    }
    __syncthreads();
  }
  // epilogue: pf = relu(pfT + b2) in packed f16 -> store
  unsigned pc[4];
  pc[0] = pkrtz(b2[q*4 + 0], b2[q*4 + 1]);
  pc[1] = pkrtz(b2[q*4 + 2], b2[q*4 + 3]);
  pc[2] = pkrtz(b2[16 + q*4 + 0], b2[16 + q*4 + 1]);
  pc[3] = pkrtz(b2[16 + q*4 + 2], b2[16 + q*4 + 3]);
#pragma unroll
  for (int et = 0; et < 4; ++et){
    half8 pf = cvtpackbr(apf[et][0], apf[et][1], pc);
    *(half8*)(pfp + (blockIdx.x*16 + wave*4 + et)*512 + lane*8) = pf;
  }
}

// ---- initial f1 (transposed), 16 dets per wave, 4 waves/WG ----
__global__ __launch_bounds__(256) void kF1(const float* detF, const _Float16* fc1p,
    const float* fb, _Float16* f1G){
  int lane = threadIdx.x & 63, wave = threadIdx.x >> 6;
  int q = lane >> 4, e = lane & 15;
  int det = (blockIdx.x * 4 + wave) * 16 + e;
  const f32x4 fz = {0.f, 0.f, 0.f, 0.f};
  half8 ff[4];
#pragma unroll
  for (int s = 0; s < 4; ++s){
    const float* p = detF + det*128 + s*32 + q*4;
    f32x4 x0 = *(const f32x4*)(p);
    f32x4 x1 = *(const f32x4*)(p + 16);
    union { unsigned w[4]; half8 h; } u;
    u.w[0] = pkrtz(x0[0], x0[1]); u.w[1] = pkrtz(x0[2], x0[3]);
    u.w[2] = pkrtz(x1[0], x1[1]); u.w[3] = pkrtz(x1[2], x1[3]);
    ff[s] = u.h;
  }
#pragma unroll
  for (int m = 0; m < 2; ++m){
    f32x4 a = fz;
#pragma unroll
    for (int s = 0; s < 4; ++s)
      a = mfma16(ldg8(fc1p + (m*4+s)*512 + lane*8), ff[s], a);
    f32x4 bv = *(const f32x4*)(fb + m*16 + q*4);
    unsigned u0 = pkrtz(fmaxf(a[0]+bv[0],0.f), fmaxf(a[1]+bv[1],0.f));
    unsigned u1 = pkrtz(fmaxf(a[2]+bv[2],0.f), fmaxf(a[3]+bv[3],0.f));
    *(unsigned*)(f1G + det*32 + q*8 + m*4)     = u0;
    *(unsigned*)(f1G + det*32 + q*8 + m*4 + 2) = u1;
  }
}

// ---- one graph block: edge MLP + segment max + post MLPs + residual + next f1 ----
// grid 512 x 256: 16 dets/WG, 4 dets/wave, weights in VGPRs.
// XCD-bijective swizzle; depth-1 pipeline on the det loop (nI/Bc prefetch);
// phase B is race-free: each wave owns its 2 out-rows; next-f1 fragments are
// staged through LDS behind a barrier (values are wave-invariant per lane).
__global__ __launch_bounds__(256) void kBlk(const _Float16* pfp, const _Float16* f1in,
    _Float16* f1out, const int* nI, const _Float16* pw1p, const _Float16* pw2p,
    const _Float16* post0p, const _Float16* post1p, const _Float16* outp, const _Float16* fc1pn,
    const float* bb1, const float* bb2, const float* pb0, const float* pb1, const float* ob,
    const float* fbn, const float* fin, float* fout, int doF1){
  __shared__ __align__(16) _Float16 poolS[1024];  // [2 halves][16 dets][32 halfs]
  __shared__ __align__(16) _Float16 ffS[2048];    // next-f1 B-frag staging (4 waves x 64 x 8)
  int tid = threadIdx.x, lane = tid & 63, wave = tid >> 6;
  int q = lane >> 4, e = lane & 15;
  int bid = blockIdx.x;
  int base = ((bid & 7) * 64 + (bid >> 3)) * 16;   // XCD-bijective det range
  const f32x4 fz = {0.f, 0.f, 0.f, 0.f};

  half8 aW1[4][3], aW2[4][2];
  f32x4 b1v[4];
  unsigned b2p[8];   // pw2 bias, packed to match cvtpack slot order
#pragma unroll
  for (int m = 0; m < 4; ++m){
#pragma unroll
    for (int k = 0; k < 3; ++k) aW1[m][k] = ldg8(pw1p + (m*3+k)*512 + lane*8);
#pragma unroll
    for (int k = 0; k < 2; ++k) aW2[m][k] = ldg8(pw2p + (m*2+k)*512 + lane*8);
    b1v[m] = *(const f32x4*)(bb1 + m*16 + q*4);
    b2p[m*2+0] = pkrtz(bb2[m*16 + q*4 + 0], bb2[m*16 + q*4 + 1]);
    b2p[m*2+1] = pkrtz(bb2[m*16 + q*4 + 2], bb2[m*16 + q*4 + 3]);
  }

  // ---- phase A: edge MLP + packed-f16 pooling (4 dets/wave, depth-1 pipeline) ----
  int nnC[4]; half8 BcC;
  {
    int det0 = base + wave*4;
#pragma unroll
    for (int et = 0; et < 4; ++et) nnC[et] = nI[det0*64 + et*16 + e];
    BcC = ldg8(f1in + det0*32 + q*8);
  }
#pragma unroll 1
  for (int dd = 0; dd < 4; ++dd){
    int d = wave*4 + dd;
    int det = base + d;
    // current det's gathers (addresses ready: nnC prefetched last iteration)
    half8 Bpf[4], Bn[4];
#pragma unroll
    for (int et = 0; et < 4; ++et){
      Bpf[et] = ldg8(pfp + (det*4+et)*512 + lane*8);
      Bn[et]  = ldg8(f1in + nnC[et]*32 + q*8);
    }
    // prefetch next det's indices + c-row (latency hidden under this det's compute)
    int nnN[4]; half8 BcN;
    if (dd < 3){
      int detn = det + 1;
#pragma unroll
      for (int et = 0; et < 4; ++et) nnN[et] = nI[detn*64 + et*16 + e];
      BcN = ldg8(f1in + detn*32 + q*8);
    }
    // et-invariant c-contribution, folded into pw1 bias
    f32x4 bcb[4];
#pragma unroll
    for (int m = 0; m < 4; ++m){
      f32x4 dc = mfma16(aW1[m][1], BcC, fz);
#pragma unroll
      for (int r = 0; r < 4; ++r) bcb[m][r] = dc[r] + b1v[m][r];
    }
    unsigned pm[8];
#pragma unroll
    for (int i = 0; i < 8; ++i) pm[i] = 0xFC00FC00u;   // (-inf, -inf)
#pragma unroll
    for (int et = 0; et < 4; ++et){
      f32x4 acc[4];
#pragma unroll
      for (int m = 0; m < 4; ++m){
        acc[m] = mfma16(aW1[m][0], Bpf[et], fz);
        acc[m] = mfma16(aW1[m][2], Bn[et], acc[m]);
      }
      f32x4 r0, r1, r2, r3;
#pragma unroll
      for (int r = 0; r < 4; ++r){
        r0[r] = fmaxf(acc[0][r] + bcb[0][r], 0.f);
        r1[r] = fmaxf(acc[1][r] + bcb[1][r], 0.f);
        r2[r] = fmaxf(acc[2][r] + bcb[2][r], 0.f);
        r3[r] = fmaxf(acc[3][r] + bcb[3][r], 0.f);
      }
      half8 h1a = cvtpack(r0, r1);
      half8 h1b = cvtpack(r2, r3);
      f32x4 a2[4];
#pragma unroll
      for (int m = 0; m < 4; ++m){
        a2[m] = mfma16(aW2[m][0], h1a, fz);
        a2[m] = mfma16(aW2[m][1], h1b, a2[m]);
      }
      // pack raw a2 (bias+relu deferred past the max) and pk-max accumulate
      union { half8 h; unsigned w[4]; } uA, uB;
      uA.h = cvtpack(a2[0], a2[1]);
      uB.h = cvtpack(a2[2], a2[3]);
#pragma unroll
      for (int i = 0; i < 4; ++i){
        pm[i]   = hmax2u(pm[i],   uA.w[i]);
        pm[4+i] = hmax2u(pm[4+i], uB.w[i]);
      }
    }
    // butterfly max over the 16 edge columns (packed)
#pragma unroll
    for (int s = 1; s <= 8; s <<= 1){
#pragma unroll
      for (int i = 0; i < 8; ++i)
        pm[i] = hmax2u(pm[i], __shfl_xor(pm[i], s));
    }
    // deferred bias + relu (packed)
#pragma unroll
    for (int i = 0; i < 8; ++i)
      pm[i] = hmax2u(hadd2u(pm[i], b2p[i]), 0u);
    if (e == 0){
      union { unsigned w[4]; half8 h; } o0, o1;
#pragma unroll
      for (int i = 0; i < 4; ++i){ o0.w[i] = pm[i]; o1.w[i] = pm[4+i]; }
      *(half8*)(poolS + d*32 + q*8)       = o0.h;   // k 0..31
      *(half8*)(poolS + 512 + d*32 + q*8) = o1.h;   // k 32..63
    }
    // rotate the pipeline registers
    if (dd < 3){
#pragma unroll
      for (int et = 0; et < 4; ++et) nnC[et] = nnN[et];
      BcC = BcN;
    }
  }
  __syncthreads();

  // ---- phase B: post MLPs + residual + next f1 (16 dets as frag cols) ----
  half8 Bp0 = *(const half8*)(poolS + e*32 + q*8);
  half8 Bp1 = *(const half8*)(poolS + 512 + e*32 + q*8);
  int det = base + e;
  f32x4 t0[4];
#pragma unroll
  for (int m = 0; m < 4; ++m){
    f32x4 a = mfma16(ldg8(post0p + (m*2)*512   + lane*8), Bp0, fz);
    a = mfma16(ldg8(post0p + (m*2+1)*512 + lane*8), Bp1, a);
    f32x4 bv = *(const f32x4*)(pb0 + m*16 + q*4);
#pragma unroll
    for (int r = 0; r < 4; ++r) t0[m][r] = fmaxf(a[r] + bv[r], 0.f);
  }
  half8 p1a = cvtpack(t0[0], t0[1]);
  half8 p1b = cvtpack(t0[2], t0[3]);
#pragma unroll
  for (int m = 0; m < 4; ++m){
    f32x4 a = mfma16(ldg8(post1p + (m*2)*512   + lane*8), p1a, fz);
    a = mfma16(ldg8(post1p + (m*2+1)*512 + lane*8), p1b, a);
    f32x4 bv = *(const f32x4*)(pb1 + m*16 + q*4);
#pragma unroll
    for (int r = 0; r < 4; ++r) t0[m][r] = fmaxf(a[r] + bv[r], 0.f);
  }
  half8 p2a = cvtpack(t0[0], t0[1]);
  half8 p2b = cvtpack(t0[2], t0[3]);
  // each wave owns out-rows m0 = 2*wave, m0+1 — no cross-wave read/write overlap
  int m0 = wave*2, m1 = m0 + 1;
  f32x4 fr0, fr1;
  {
    f32x4 a = mfma16(ldg8(outp + (m0*2)*512   + lane*8), p2a, fz);
    a = mfma16(ldg8(outp + (m0*2+1)*512 + lane*8), p2b, a);
    f32x4 bv = *(const f32x4*)(ob + m0*16 + q*4);
    f32x4 fv = *(const f32x4*)(fin + det*128 + m0*16 + q*4);
#pragma unroll
    for (int r = 0; r < 4; ++r) fr0[r] = fmaxf(fv[r] + a[r] + bv[r], 0.f);
  }
  {
    f32x4 a = mfma16(ldg8(outp + (m1*2)*512   + lane*8), p2a, fz);
    a = mfma16(ldg8(outp + (m1*2+1)*512 + lane*8), p2b, a);
    f32x4 bv = *(const f32x4*)(ob + m1*16 + q*4);
    f32x4 fv = *(const f32x4*)(fin + det*128 + m1*16 + q*4);
#pragma unroll
    for (int r = 0; r < 4; ++r) fr1[r] = fmaxf(fv[r] + a[r] + bv[r], 0.f);
  }
  *(f32x4*)(fout + det*128 + m0*16 + q*4) = fr0;
  *(f32x4*)(fout + det*128 + m1*16 + q*4) = fr1;
  if (doF1){
    // stage this wave's next-f1 B-frag (s = wave); per-lane values are
    // wave-invariant (D-layout depends only on (q,e)), so s=w matches s=0..3
    half8 ffw = cvtpack(fr0, fr1);
    *(half8*)(ffS + wave*512 + lane*8) = ffw;
    __syncthreads();
    if (wave == 0){
#pragma unroll
      for (int m = 0; m < 2; ++m){
        f32x4 a = fz;
#pragma unroll
        for (int s = 0; s < 4; ++s){
          half8 fs = *(const half8*)(ffS + s*512 + lane*8);
          a = mfma16(ldg8(fc1pn + (m*4+s)*512 + lane*8), fs, a);
        }
        f32x4 bv = *(const f32x4*)(fbn + m*16 + q*4);
        unsigned u0 = pkrtz(fmaxf(a[0]+bv[0],0.f), fmaxf(a[1]+bv[1],0.f));
        unsigned u1 = pkrtz(fmaxf(a[2]+bv[2],0.f), fmaxf(a[3]+bv[3],0.f));
        *(unsigned*)(f1out + det*32 + q*8 + m*4)     = u0;
        *(unsigned*)(f1out + det*32 + q*8 + m*4 + 2) = u1;
      }
    }
  }
}

extern "C" void kernel_launch(void* const* d_in, const int* in_sizes, int n_in,
                              void* d_out, int out_size, void* d_ws, size_t ws_size,
                              hipStream_t stream){
  const float* detScores   = (const float*)d_in[0];
  const float* dtBoxes     = (const float*)d_in[1];
  const float* detFeatures = (const float*)d_in[2];
  const int*   cI          = (const int*)d_in[3];
  const int*   nI          = (const int*)d_in[4];
  const float* pwW0 = (const float*)d_in[5];
  const float* pwb0 = (const float*)d_in[6];
  const float* pwW1 = (const float*)d_in[7];
  const float* pwb1 = (const float*)d_in[8];
  const float* pwW2 = (const float*)d_in[9];
  const float* pwb2 = (const float*)d_in[10];
  const float* fc1W = (const float*)d_in[11];
  const float* fc1b = (const float*)d_in[12];
  const float* pw1W = (const float*)d_in[13];
  const float* pw1b = (const float*)d_in[14];
  const float* pw2W = (const float*)d_in[15];
  const float* pw2b = (const float*)d_in[16];
  const float* postW = (const float*)d_in[17];
  const float* postb = (const float*)d_in[18];
  const float* outW  = (const float*)d_in[19];
  const float* outb  = (const float*)d_in[20];

  _Float16* wsh  = (_Float16*)d_ws;
  float*    fbuf = (float*)((char*)d_ws + OFF_FBUF_BYTES);
  _Float16* f1A  = wsh + OFF_F1A;
  _Float16* f1B  = wsh + OFF_F1B;
  _Float16* pfp  = wsh + OFF_PFP;

  kPrep<<<160, 256, 0, stream>>>(pwW0, pwb0, pwW1, pwW2, fc1W, pw1W, pw2W, postW, outW, wsh);
  kF1<<<128, 256, 0, stream>>>(detFeatures, wsh + OFF_FC1P, fc1b, f1A);
  kP<<<2048, 256, 0, stream>>>(detScores, dtBoxes, cI, nI, pwb1, pwb2,
      wsh + OFF_W0P, wsh + OFF_W1P, wsh + OFF_W2P, pfp);

  for (int i = 0; i < 8; ++i){
    int last = (i == 7);
    _Float16* fin1  = (i & 1) ? f1B : f1A;
    _Float16* fout1 = (i & 1) ? f1A : f1B;
    kBlk<<<512, 256, 0, stream>>>(pfp, fin1, fout1, nI,
        wsh + OFF_PW1P + i*6144, wsh + OFF_PW2P + i*4096,
        wsh + OFF_POSTP + i*8192, wsh + OFF_POSTP + i*8192 + 4096, wsh + OFF_OUTP + i*8192,
        wsh + OFF_FC1P + ((i+1) & 7)*4096,
        pw1b + i*64, pw2b + i*64, postb + i*128, postb + i*128 + 64, outb + i*128,
        fc1b + ((i+1) & 7)*32,
        (i == 0) ? detFeatures : fbuf, last ? (float*)d_out : fbuf, last ? 0 : 1);
  }
}